// Round 3
// baseline (3215.848 us; speedup 1.0000x reference)
//
#include <hip/hip_runtime.h>
#include <hip/hip_bf16.h>
#include <math.h>

// ---------------------------------------------------------------------------
// 3-layer GAT forward, f32 compute, f32 output.
// Round 3: output dtype fixed to float32 (reference returns f32; the bf16
// threshold floor was not applied and expected-npz size matches f32).
// ---------------------------------------------------------------------------

__device__ __forceinline__ float block_reduce_sum_bcast(float v) {
#pragma unroll
  for (int off = 32; off > 0; off >>= 1) v += __shfl_down(v, off, 64);
  __shared__ float tmp[4];
  __shared__ float res;
  int lane = threadIdx.x & 63, w = threadIdx.x >> 6;
  if (lane == 0) tmp[w] = v;
  __syncthreads();
  if (threadIdx.x == 0) res = tmp[0] + tmp[1] + tmp[2] + tmp[3];
  __syncthreads();
  float out = res;
  __syncthreads();
  return out;
}

__device__ __forceinline__ float block_reduce_max_bcast(float v) {
#pragma unroll
  for (int off = 32; off > 0; off >>= 1) v = fmaxf(v, __shfl_down(v, off, 64));
  __shared__ float tmpm[4];
  __shared__ float resm;
  int lane = threadIdx.x & 63, w = threadIdx.x >> 6;
  if (lane == 0) tmpm[w] = v;
  __syncthreads();
  if (threadIdx.x == 0) resm = fmaxf(fmaxf(tmpm[0], tmpm[1]), fmaxf(tmpm[2], tmpm[3]));
  __syncthreads();
  float out = resm;
  __syncthreads();
  return out;
}

// ---------------------------------------------------------------------------
// edge_index dtype detection (int64 vs int32), kept for robustness.
// ---------------------------------------------------------------------------
__global__ void detect_kernel(const int* __restrict__ ei32, int* __restrict__ flag) {
  __shared__ int cnt;
  if (threadIdx.x == 0) cnt = 0;
  __syncthreads();
  int zeros = 0;
  for (int i = threadIdx.x; i < 1024; i += 256) {
    if (ei32[2 * i + 1] == 0) zeros++;
  }
  atomicAdd(&cnt, zeros);
  __syncthreads();
  if (threadIdx.x == 0) *flag = (cnt > 900) ? 1 : 0;
}

__global__ void convert_kernel(const void* __restrict__ ei, const int* __restrict__ flag,
                               int E, int* __restrict__ src, int* __restrict__ dst) {
  int i = blockIdx.x * blockDim.x + threadIdx.x;
  if (i >= E) return;
  if (*flag) {
    const long long* p = (const long long*)ei;
    src[i] = (int)p[i];
    dst[i] = (int)p[E + i];
  } else {
    const int* p = (const int*)ei;
    src[i] = p[i];
    dst[i] = p[E + i];
  }
}

// ---------------------------------------------------------------------------
// C[M][Nout] = A[M][K] @ B[K][Nout], row-major, f32.
// ---------------------------------------------------------------------------
__global__ __launch_bounds__(256) void gemm_f32(const float* __restrict__ A,
                                                const float* __restrict__ B,
                                                float* __restrict__ C,
                                                int M, int K, int Nout) {
  const int BM = 64, BN = 64, BK = 16;
  __shared__ float As[BK][BM + 1];
  __shared__ float Bs[BK][BN + 1];
  int tid = threadIdx.x;
  int tx = tid % 16, ty = tid / 16;
  int row0 = blockIdx.y * BM, col0 = blockIdx.x * BN;
  float acc[4][4] = {};
  for (int k0 = 0; k0 < K; k0 += BK) {
    for (int t = tid; t < BM * BK; t += 256) {
      int m = t / BK, kk = t % BK;
      int gr = row0 + m;
      As[kk][m] = (gr < M) ? A[(size_t)gr * K + k0 + kk] : 0.f;
    }
    for (int t = tid; t < BK * BN; t += 256) {
      int kk = t / BN, n = t % BN;
      Bs[kk][n] = B[(size_t)(k0 + kk) * Nout + col0 + n];
    }
    __syncthreads();
#pragma unroll
    for (int kk = 0; kk < BK; ++kk) {
      float a[4], b[4];
#pragma unroll
      for (int i = 0; i < 4; ++i) a[i] = As[kk][ty * 4 + i];
#pragma unroll
      for (int j = 0; j < 4; ++j) b[j] = Bs[kk][tx * 4 + j];
#pragma unroll
      for (int i = 0; i < 4; ++i)
#pragma unroll
        for (int j = 0; j < 4; ++j) acc[i][j] += a[i] * b[j];
    }
    __syncthreads();
  }
  for (int i = 0; i < 4; ++i) {
    int r = row0 + ty * 4 + i;
    if (r < M) {
#pragma unroll
      for (int j = 0; j < 4; ++j)
        C[(size_t)r * Nout + col0 + tx * 4 + j] = acc[i][j];
    }
  }
}

// ---------------------------------------------------------------------------
// al_src[n] = dot(xw[n,:], a_s); al_dst[n] = dot(xw[n,:], a_d)
// ---------------------------------------------------------------------------
__global__ __launch_bounds__(256) void compute_al(const float* __restrict__ xw,
                                                  const float* __restrict__ a_s,
                                                  const float* __restrict__ a_d,
                                                  float* __restrict__ als,
                                                  float* __restrict__ ald, int F) {
  int n = blockIdx.x;
  const float* row = xw + (size_t)n * F;
  float s1 = 0.f, s2 = 0.f;
  for (int f = threadIdx.x; f < F; f += 256) {
    float v = row[f];
    s1 += v * a_s[f];
    s2 += v * a_d[f];
  }
  float r1 = block_reduce_sum_bcast(s1);
  float r2 = block_reduce_sum_bcast(s2);
  if (threadIdx.x == 0) {
    als[n] = r1;
    ald[n] = r2;
  }
}

// ---------------------------------------------------------------------------
// CSR build
// ---------------------------------------------------------------------------
__global__ void count_kernel(const int* __restrict__ dst, int* __restrict__ counts, int E) {
  int i = blockIdx.x * blockDim.x + threadIdx.x;
  if (i < E) atomicAdd(&counts[dst[i]], 1);
}

__global__ __launch_bounds__(1024) void scan_kernel(const int* __restrict__ counts,
                                                    int* __restrict__ rowptr,
                                                    int* __restrict__ cursor, int Nn) {
  __shared__ int part[1024];
  int tid = threadIdx.x;
  int chunk = (Nn + 1023) / 1024;
  int base = tid * chunk;
  int s = 0;
  for (int i = 0; i < chunk; ++i) {
    int idx = base + i;
    if (idx < Nn) s += counts[idx];
  }
  part[tid] = s;
  __syncthreads();
  for (int off = 1; off < 1024; off <<= 1) {
    int v = 0;
    if (tid >= off) v = part[tid - off];
    __syncthreads();
    if (tid >= off) part[tid] += v;
    __syncthreads();
  }
  int run = (tid == 0) ? 0 : part[tid - 1];
  for (int i = 0; i < chunk; ++i) {
    int idx = base + i;
    if (idx < Nn) {
      rowptr[idx] = run;
      cursor[idx] = run;
      run += counts[idx];
    }
  }
  if (tid == 1023) rowptr[Nn] = part[1023];
}

__global__ void fill_kernel(const int* __restrict__ src, const int* __restrict__ dst,
                            int* __restrict__ cursor, int* __restrict__ eidx, int E) {
  int i = blockIdx.x * blockDim.x + threadIdx.x;
  if (i < E) {
    int pos = atomicAdd(&cursor[dst[i]], 1);
    eidx[pos] = src[i];
  }
}

// ---------------------------------------------------------------------------
// Per-dst-node softmax attention + weighted gather + bias + ReLU.
// One block (256 threads) per node. F == 256*FPT. Self-loop appended.
// ---------------------------------------------------------------------------
template <int FPT>
__global__ __launch_bounds__(256) void aggregate(const float* __restrict__ xw,
                                                 const float* __restrict__ als,
                                                 const float* __restrict__ ald,
                                                 const int* __restrict__ rowptr,
                                                 const int* __restrict__ eidx,
                                                 const float* __restrict__ bias,
                                                 float* __restrict__ out, int F) {
  int n = blockIdx.x;
  int tid = threadIdx.x;
  int beg = rowptr[n], end = rowptr[n + 1];
  int deg = end - beg;           // incoming edges (self-loop handled as index deg)
  float aldn = ald[n];

  // pass A: segment max over deg+1 entries
  float lm = -INFINITY;
  for (int j = tid; j < deg; j += 256) {
    int s = eidx[beg + j];
    float e = als[s] + aldn;
    e = (e > 0.f) ? e : 0.2f * e;
    lm = fmaxf(lm, e);
  }
  if (tid == 0) {
    float e = als[n] + aldn;
    e = (e > 0.f) ? e : 0.2f * e;
    lm = fmaxf(lm, e);
  }
  float m = block_reduce_max_bcast(lm);

  // pass B: denom
  float ls = 0.f;
  for (int j = tid; j < deg; j += 256) {
    int s = eidx[beg + j];
    float e = als[s] + aldn;
    e = (e > 0.f) ? e : 0.2f * e;
    ls += expf(e - m);
  }
  if (tid == 0) {
    float e = als[n] + aldn;
    e = (e > 0.f) ? e : 0.2f * e;
    ls += expf(e - m);
  }
  float denom = block_reduce_sum_bcast(ls) + 1e-16f;
  float inv_denom = 1.f / denom;

  // pass C: weighted sum of xw[src] rows
  float acc[FPT];
#pragma unroll
  for (int i = 0; i < FPT; ++i) acc[i] = 0.f;

  __shared__ float alpha_sh[256];
  __shared__ int src_sh[256];
  int total = deg + 1;
  for (int c0 = 0; c0 < total; c0 += 256) {
    int j = c0 + tid;
    if (j < total) {
      int s = (j < deg) ? eidx[beg + j] : n;
      float e = als[s] + aldn;
      e = (e > 0.f) ? e : 0.2f * e;
      alpha_sh[tid] = expf(e - m) * inv_denom;
      src_sh[tid] = s;
    }
    __syncthreads();
    int cn = min(256, total - c0);
    for (int jj = 0; jj < cn; ++jj) {
      float al = alpha_sh[jj];
      const float* row = xw + (size_t)src_sh[jj] * F;
#pragma unroll
      for (int i = 0; i < FPT; ++i) acc[i] += al * row[tid + i * 256];
    }
    __syncthreads();
  }

  // epilogue: bias + ReLU
  float* orow = out + (size_t)n * F;
#pragma unroll
  for (int i = 0; i < FPT; ++i) {
    float v = acc[i] + bias[tid + i * 256];
    orow[tid + i * 256] = fmaxf(v, 0.f);
  }
}

// ---------------------------------------------------------------------------
// Row L2 normalize (eps 1e-12), write f32.
// ---------------------------------------------------------------------------
__global__ __launch_bounds__(256) void normalize_kernel(const float* __restrict__ h,
                                                        float* __restrict__ out,
                                                        int F) {
  int n = blockIdx.x;
  const float* row = h + (size_t)n * F;
  float ss = 0.f;
  for (int f = threadIdx.x; f < F; f += 256) {
    float v = row[f];
    ss += v * v;
  }
  float tot = block_reduce_sum_bcast(ss);
  float inv = 1.f / fmaxf(sqrtf(tot), 1e-12f);
  for (int f = threadIdx.x; f < F; f += 256) {
    out[(size_t)n * F + f] = row[f] * inv;
  }
}

// ---------------------------------------------------------------------------
extern "C" void kernel_launch(void* const* d_in, const int* in_sizes, int n_in,
                              void* d_out, int out_size, void* d_ws, size_t ws_size,
                              hipStream_t stream) {
  const float* x   = (const float*)d_in[0];
  const void*  ei  = d_in[1];
  const float* W1  = (const float*)d_in[2];
  const float* W2  = (const float*)d_in[3];
  const float* W3  = (const float*)d_in[4];
  const float* a1s = (const float*)d_in[5];
  const float* a1d = (const float*)d_in[6];
  const float* a2s = (const float*)d_in[7];
  const float* a2d = (const float*)d_in[8];
  const float* a3s = (const float*)d_in[9];
  const float* a3d = (const float*)d_in[10];
  const float* b1  = (const float*)d_in[11];
  const float* b2  = (const float*)d_in[12];
  const float* b3  = (const float*)d_in[13];

  const int N = in_sizes[0] / 256;  // 10000
  const int E = in_sizes[1] / 2;    // 80000

  char* ws = (char*)d_ws;
  size_t off = 0;
  auto alloc = [&](size_t bytes) -> void* {
    void* p = ws + off;
    off += (bytes + 255) & ~(size_t)255;
    return p;
  };
  float* bufA  = (float*)alloc((size_t)N * 2048 * 4);
  float* bufB  = (float*)alloc((size_t)N * 2048 * 4);
  float* als   = (float*)alloc((size_t)N * 4);
  float* ald   = (float*)alloc((size_t)N * 4);
  int* counts  = (int*)alloc((size_t)N * 4);
  int* rowptr  = (int*)alloc((size_t)(N + 1) * 4);
  int* cursor  = (int*)alloc((size_t)N * 4);
  int* eidx    = (int*)alloc((size_t)E * 4);
  int* src32   = (int*)alloc((size_t)E * 4);
  int* dst32   = (int*)alloc((size_t)E * 4);
  int* flag    = (int*)alloc(256);

  // edge_index dtype detect + convert to int32 src/dst
  detect_kernel<<<1, 256, 0, stream>>>((const int*)ei, flag);
  convert_kernel<<<(E + 255) / 256, 256, 0, stream>>>(ei, flag, E, src32, dst32);

  // CSR build (by dst)
  hipMemsetAsync(counts, 0, (size_t)N * 4, stream);
  count_kernel<<<(E + 255) / 256, 256, 0, stream>>>(dst32, counts, E);
  scan_kernel<<<1, 1024, 0, stream>>>(counts, rowptr, cursor, N);
  fill_kernel<<<(E + 255) / 256, 256, 0, stream>>>(src32, dst32, cursor, eidx, E);

  dim3 blk(256);
  int mblocks = (N + 63) / 64;

  // layer 1: Fin=256, Fout=2048
  gemm_f32<<<dim3(2048 / 64, mblocks), blk, 0, stream>>>(x, W1, bufA, N, 256, 2048);
  compute_al<<<N, blk, 0, stream>>>(bufA, a1s, a1d, als, ald, 2048);
  aggregate<8><<<N, blk, 0, stream>>>(bufA, als, ald, rowptr, eidx, b1, bufB, 2048);

  // layer 2: Fin=2048, Fout=2048
  gemm_f32<<<dim3(2048 / 64, mblocks), blk, 0, stream>>>(bufB, W2, bufA, N, 2048, 2048);
  compute_al<<<N, blk, 0, stream>>>(bufA, a2s, a2d, als, ald, 2048);
  aggregate<8><<<N, blk, 0, stream>>>(bufA, als, ald, rowptr, eidx, b2, bufB, 2048);

  // layer 3: Fin=2048, Fout=1024
  gemm_f32<<<dim3(1024 / 64, mblocks), blk, 0, stream>>>(bufB, W3, bufA, N, 2048, 1024);
  compute_al<<<N, blk, 0, stream>>>(bufA, a3s, a3d, als, ald, 1024);
  aggregate<4><<<N, blk, 0, stream>>>(bufA, als, ald, rowptr, eidx, b3, bufB, 1024);

  normalize_kernel<<<N, blk, 0, stream>>>(bufB, (float*)d_out, 1024);
}

// Round 4
// 634.373 us; speedup vs baseline: 5.0693x; 5.0693x over previous
//
#include <hip/hip_runtime.h>
#include <hip/hip_bf16.h>
#include <math.h>

// ---------------------------------------------------------------------------
// 3-layer GAT forward. Round 4: GEMMs -> bf16 MFMA (16x16x32), f32 accum.
// Weights pre-transposed to [N][K] bf16; activations carried as bf16 between
// layers; attention logits / softmax / aggregation stay f32.
// ---------------------------------------------------------------------------

typedef __attribute__((ext_vector_type(8))) short short8;
typedef __attribute__((ext_vector_type(4))) float f32x4;

__device__ __forceinline__ float block_reduce_sum_bcast(float v) {
#pragma unroll
  for (int off = 32; off > 0; off >>= 1) v += __shfl_down(v, off, 64);
  __shared__ float tmp[4];
  __shared__ float res;
  int lane = threadIdx.x & 63, w = threadIdx.x >> 6;
  if (lane == 0) tmp[w] = v;
  __syncthreads();
  if (threadIdx.x == 0) res = tmp[0] + tmp[1] + tmp[2] + tmp[3];
  __syncthreads();
  float out = res;
  __syncthreads();
  return out;
}

__device__ __forceinline__ float block_reduce_max_bcast(float v) {
#pragma unroll
  for (int off = 32; off > 0; off >>= 1) v = fmaxf(v, __shfl_down(v, off, 64));
  __shared__ float tmpm[4];
  __shared__ float resm;
  int lane = threadIdx.x & 63, w = threadIdx.x >> 6;
  if (lane == 0) tmpm[w] = v;
  __syncthreads();
  if (threadIdx.x == 0) resm = fmaxf(fmaxf(tmpm[0], tmpm[1]), fmaxf(tmpm[2], tmpm[3]));
  __syncthreads();
  float out = resm;
  __syncthreads();
  return out;
}

// ---------------------------------------------------------------------------
// edge_index dtype detection (int64 vs int32), kept for robustness.
// ---------------------------------------------------------------------------
__global__ void detect_kernel(const int* __restrict__ ei32, int* __restrict__ flag) {
  __shared__ int cnt;
  if (threadIdx.x == 0) cnt = 0;
  __syncthreads();
  int zeros = 0;
  for (int i = threadIdx.x; i < 1024; i += 256) {
    if (ei32[2 * i + 1] == 0) zeros++;
  }
  atomicAdd(&cnt, zeros);
  __syncthreads();
  if (threadIdx.x == 0) *flag = (cnt > 900) ? 1 : 0;
}

__global__ void convert_kernel(const void* __restrict__ ei, const int* __restrict__ flag,
                               int E, int* __restrict__ src, int* __restrict__ dst) {
  int i = blockIdx.x * blockDim.x + threadIdx.x;
  if (i >= E) return;
  if (*flag) {
    const long long* p = (const long long*)ei;
    src[i] = (int)p[i];
    dst[i] = (int)p[E + i];
  } else {
    const int* p = (const int*)ei;
    src[i] = p[i];
    dst[i] = p[E + i];
  }
}

// ---------------------------------------------------------------------------
// f32 -> bf16 elementwise convert (x features).
// ---------------------------------------------------------------------------
__global__ __launch_bounds__(256) void convert_f32_bf16(const float* __restrict__ in,
                                                        __hip_bfloat16* __restrict__ out,
                                                        int n) {
  int i = blockIdx.x * blockDim.x + threadIdx.x;
  if (i < n) out[i] = __float2bfloat16(in[i]);
}

// ---------------------------------------------------------------------------
// Transpose W [K][N] f32 -> Wt [N][K] bf16.  32x32 tiles, 256 threads.
// ---------------------------------------------------------------------------
__global__ __launch_bounds__(256) void transpose_w(const float* __restrict__ W,
                                                   __hip_bfloat16* __restrict__ Wt,
                                                   int K, int Nout) {
  __shared__ float t[32][33];
  int tx = threadIdx.x & 31, ty = threadIdx.x >> 5;  // 32 x 8
  int n0 = blockIdx.x * 32, k0 = blockIdx.y * 32;
#pragma unroll
  for (int i = 0; i < 4; ++i) {
    int k = k0 + ty + i * 8;
    t[ty + i * 8][tx] = W[(size_t)k * Nout + n0 + tx];
  }
  __syncthreads();
#pragma unroll
  for (int i = 0; i < 4; ++i) {
    int n = n0 + ty + i * 8;
    Wt[(size_t)n * K + k0 + tx] = __float2bfloat16(t[tx][ty + i * 8]);
  }
}

// ---------------------------------------------------------------------------
// C[M][Nout](f32) = A[M][K](bf16, row-major) @ Bt[Nout][K](bf16)^T
// 128x128 tile, BK=32, 4 waves, mfma_f32_16x16x32_bf16.
// LDS rows padded to 40 shorts (80 B) -> <=2-way bank aliasing (free).
// ---------------------------------------------------------------------------
__global__ __launch_bounds__(256) void gemm_bf16(const ushort* __restrict__ A,
                                                 const ushort* __restrict__ Bt,
                                                 float* __restrict__ C,
                                                 int M, int K, int Nout) {
  __shared__ ushort As[128 * 40];
  __shared__ ushort Bs[128 * 40];
  int tid = threadIdx.x;
  int lane = tid & 63, w = tid >> 6;
  int wr = (w >> 1) * 64, wc = (w & 1) * 64;
  int l15 = lane & 15, lhi = lane >> 4;
  int row0 = blockIdx.y * 128, col0 = blockIdx.x * 128;
  f32x4 acc[4][4] = {};

  for (int k0 = 0; k0 < K; k0 += 32) {
    // stage A and Bt tiles: 512 short8 vectors each half, 2 per thread
#pragma unroll
    for (int i = 0; i < 2; ++i) {
      int v = tid + 256 * i;
      int r = v >> 2, ks = v & 3;
      int gr = row0 + r;
      short8 av = {};
      if (gr < M) av = *(const short8*)(A + (size_t)gr * K + k0 + ks * 8);
      *(short8*)(&As[r * 40 + ks * 8]) = av;
      int gc = col0 + r;  // Nout multiple of 128 -> always in range
      short8 bv = *(const short8*)(Bt + (size_t)gc * K + k0 + ks * 8);
      *(short8*)(&Bs[r * 40 + ks * 8]) = bv;
    }
    __syncthreads();
    short8 af[4], bfr[4];
#pragma unroll
    for (int m = 0; m < 4; ++m)
      af[m] = *(const short8*)(&As[(wr + m * 16 + l15) * 40 + lhi * 8]);
#pragma unroll
    for (int n = 0; n < 4; ++n)
      bfr[n] = *(const short8*)(&Bs[(wc + n * 16 + l15) * 40 + lhi * 8]);
#pragma unroll
    for (int m = 0; m < 4; ++m)
#pragma unroll
      for (int n = 0; n < 4; ++n)
        acc[m][n] = __builtin_amdgcn_mfma_f32_16x16x32_bf16(af[m], bfr[n], acc[m][n], 0, 0, 0);
    __syncthreads();
  }

  // epilogue: D mapping col=lane&15, row=(lane>>4)*4+reg
#pragma unroll
  for (int m = 0; m < 4; ++m) {
#pragma unroll
    for (int v = 0; v < 4; ++v) {
      int r = row0 + wr + m * 16 + lhi * 4 + v;
      if (r < M) {
#pragma unroll
        for (int n = 0; n < 4; ++n)
          C[(size_t)r * Nout + col0 + wc + n * 16 + l15] = acc[m][n][v];
      }
    }
  }
}

// ---------------------------------------------------------------------------
// al_src[n] = dot(xw[n,:], a_s); al_dst[n] = dot(xw[n,:], a_d)
// ---------------------------------------------------------------------------
__global__ __launch_bounds__(256) void compute_al(const float* __restrict__ xw,
                                                  const float* __restrict__ a_s,
                                                  const float* __restrict__ a_d,
                                                  float* __restrict__ als,
                                                  float* __restrict__ ald, int F) {
  int n = blockIdx.x;
  const float* row = xw + (size_t)n * F;
  float s1 = 0.f, s2 = 0.f;
  for (int f = threadIdx.x; f < F; f += 256) {
    float v = row[f];
    s1 += v * a_s[f];
    s2 += v * a_d[f];
  }
  float r1 = block_reduce_sum_bcast(s1);
  float r2 = block_reduce_sum_bcast(s2);
  if (threadIdx.x == 0) {
    als[n] = r1;
    ald[n] = r2;
  }
}

// ---------------------------------------------------------------------------
// CSR build
// ---------------------------------------------------------------------------
__global__ void count_kernel(const int* __restrict__ dst, int* __restrict__ counts, int E) {
  int i = blockIdx.x * blockDim.x + threadIdx.x;
  if (i < E) atomicAdd(&counts[dst[i]], 1);
}

__global__ __launch_bounds__(1024) void scan_kernel(const int* __restrict__ counts,
                                                    int* __restrict__ rowptr,
                                                    int* __restrict__ cursor, int Nn) {
  __shared__ int part[1024];
  int tid = threadIdx.x;
  int chunk = (Nn + 1023) / 1024;
  int base = tid * chunk;
  int s = 0;
  for (int i = 0; i < chunk; ++i) {
    int idx = base + i;
    if (idx < Nn) s += counts[idx];
  }
  part[tid] = s;
  __syncthreads();
  for (int off = 1; off < 1024; off <<= 1) {
    int v = 0;
    if (tid >= off) v = part[tid - off];
    __syncthreads();
    if (tid >= off) part[tid] += v;
    __syncthreads();
  }
  int run = (tid == 0) ? 0 : part[tid - 1];
  for (int i = 0; i < chunk; ++i) {
    int idx = base + i;
    if (idx < Nn) {
      rowptr[idx] = run;
      cursor[idx] = run;
      run += counts[idx];
    }
  }
  if (tid == 1023) rowptr[Nn] = part[1023];
}

__global__ void fill_kernel(const int* __restrict__ src, const int* __restrict__ dst,
                            int* __restrict__ cursor, int* __restrict__ eidx, int E) {
  int i = blockIdx.x * blockDim.x + threadIdx.x;
  if (i < E) {
    int pos = atomicAdd(&cursor[dst[i]], 1);
    eidx[pos] = src[i];
  }
}

// ---------------------------------------------------------------------------
// Per-dst-node softmax attention + weighted gather + bias + ReLU.
// BF16OUT: write bf16 (next layer's GEMM input) or f32 (final layer).
// ---------------------------------------------------------------------------
template <int FPT, bool BF16OUT>
__global__ __launch_bounds__(256) void aggregate(const float* __restrict__ xw,
                                                 const float* __restrict__ als,
                                                 const float* __restrict__ ald,
                                                 const int* __restrict__ rowptr,
                                                 const int* __restrict__ eidx,
                                                 const float* __restrict__ bias,
                                                 void* __restrict__ out, int F) {
  int n = blockIdx.x;
  int tid = threadIdx.x;
  int beg = rowptr[n], end = rowptr[n + 1];
  int deg = end - beg;
  float aldn = ald[n];

  float lm = -INFINITY;
  for (int j = tid; j < deg; j += 256) {
    int s = eidx[beg + j];
    float e = als[s] + aldn;
    e = (e > 0.f) ? e : 0.2f * e;
    lm = fmaxf(lm, e);
  }
  if (tid == 0) {
    float e = als[n] + aldn;
    e = (e > 0.f) ? e : 0.2f * e;
    lm = fmaxf(lm, e);
  }
  float m = block_reduce_max_bcast(lm);

  float ls = 0.f;
  for (int j = tid; j < deg; j += 256) {
    int s = eidx[beg + j];
    float e = als[s] + aldn;
    e = (e > 0.f) ? e : 0.2f * e;
    ls += expf(e - m);
  }
  if (tid == 0) {
    float e = als[n] + aldn;
    e = (e > 0.f) ? e : 0.2f * e;
    ls += expf(e - m);
  }
  float denom = block_reduce_sum_bcast(ls) + 1e-16f;
  float inv_denom = 1.f / denom;

  float acc[FPT];
#pragma unroll
  for (int i = 0; i < FPT; ++i) acc[i] = 0.f;

  __shared__ float alpha_sh[256];
  __shared__ int src_sh[256];
  int total = deg + 1;
  for (int c0 = 0; c0 < total; c0 += 256) {
    int j = c0 + tid;
    if (j < total) {
      int s = (j < deg) ? eidx[beg + j] : n;
      float e = als[s] + aldn;
      e = (e > 0.f) ? e : 0.2f * e;
      alpha_sh[tid] = expf(e - m) * inv_denom;
      src_sh[tid] = s;
    }
    __syncthreads();
    int cn = min(256, total - c0);
    for (int jj = 0; jj < cn; ++jj) {
      float al = alpha_sh[jj];
      const float* row = xw + (size_t)src_sh[jj] * F;
#pragma unroll
      for (int i = 0; i < FPT; ++i) acc[i] += al * row[tid + i * 256];
    }
    __syncthreads();
  }

#pragma unroll
  for (int i = 0; i < FPT; ++i) {
    float v = fmaxf(acc[i] + bias[tid + i * 256], 0.f);
    size_t idx = (size_t)n * F + tid + i * 256;
    if (BF16OUT)
      ((__hip_bfloat16*)out)[idx] = __float2bfloat16(v);
    else
      ((float*)out)[idx] = v;
  }
}

// ---------------------------------------------------------------------------
// Row L2 normalize (eps 1e-12), write f32.
// ---------------------------------------------------------------------------
__global__ __launch_bounds__(256) void normalize_kernel(const float* __restrict__ h,
                                                        float* __restrict__ out,
                                                        int F) {
  int n = blockIdx.x;
  const float* row = h + (size_t)n * F;
  float ss = 0.f;
  for (int f = threadIdx.x; f < F; f += 256) {
    float v = row[f];
    ss += v * v;
  }
  float tot = block_reduce_sum_bcast(ss);
  float inv = 1.f / fmaxf(sqrtf(tot), 1e-12f);
  for (int f = threadIdx.x; f < F; f += 256) {
    out[(size_t)n * F + f] = row[f] * inv;
  }
}

// ---------------------------------------------------------------------------
extern "C" void kernel_launch(void* const* d_in, const int* in_sizes, int n_in,
                              void* d_out, int out_size, void* d_ws, size_t ws_size,
                              hipStream_t stream) {
  const float* x   = (const float*)d_in[0];
  const void*  ei  = d_in[1];
  const float* W1  = (const float*)d_in[2];
  const float* W2  = (const float*)d_in[3];
  const float* W3  = (const float*)d_in[4];
  const float* a1s = (const float*)d_in[5];
  const float* a1d = (const float*)d_in[6];
  const float* a2s = (const float*)d_in[7];
  const float* a2d = (const float*)d_in[8];
  const float* a3s = (const float*)d_in[9];
  const float* a3d = (const float*)d_in[10];
  const float* b1  = (const float*)d_in[11];
  const float* b2  = (const float*)d_in[12];
  const float* b3  = (const float*)d_in[13];

  const int N = in_sizes[0] / 256;  // 10000
  const int E = in_sizes[1] / 2;    // 80000

  char* ws = (char*)d_ws;
  size_t off = 0;
  auto alloc = [&](size_t bytes) -> void* {
    void* p = ws + off;
    off += (bytes + 255) & ~(size_t)255;
    return p;
  };
  float* bufA = (float*)alloc((size_t)N * 2048 * 4);          // GEMM out (f32)
  __hip_bfloat16* hbf = (__hip_bfloat16*)alloc((size_t)N * 2048 * 2);  // activations bf16 / reused f32 out L3
  __hip_bfloat16* xb  = (__hip_bfloat16*)alloc((size_t)N * 256 * 2);
  __hip_bfloat16* Wt1 = (__hip_bfloat16*)alloc((size_t)2048 * 256 * 2);
  __hip_bfloat16* Wt2 = (__hip_bfloat16*)alloc((size_t)2048 * 2048 * 2);
  __hip_bfloat16* Wt3 = (__hip_bfloat16*)alloc((size_t)1024 * 2048 * 2);
  float* als   = (float*)alloc((size_t)N * 4);
  float* ald   = (float*)alloc((size_t)N * 4);
  int* counts  = (int*)alloc((size_t)N * 4);
  int* rowptr  = (int*)alloc((size_t)(N + 1) * 4);
  int* cursor  = (int*)alloc((size_t)N * 4);
  int* eidx    = (int*)alloc((size_t)E * 4);
  int* src32   = (int*)alloc((size_t)E * 4);
  int* dst32   = (int*)alloc((size_t)E * 4);
  int* flag    = (int*)alloc(256);

  // edge_index dtype detect + convert; CSR build (by dst)
  detect_kernel<<<1, 256, 0, stream>>>((const int*)ei, flag);
  convert_kernel<<<(E + 255) / 256, 256, 0, stream>>>(ei, flag, E, src32, dst32);
  hipMemsetAsync(counts, 0, (size_t)N * 4, stream);
  count_kernel<<<(E + 255) / 256, 256, 0, stream>>>(dst32, counts, E);
  scan_kernel<<<1, 1024, 0, stream>>>(counts, rowptr, cursor, N);
  fill_kernel<<<(E + 255) / 256, 256, 0, stream>>>(src32, dst32, cursor, eidx, E);

  // bf16 prep
  convert_f32_bf16<<<(N * 256 + 255) / 256, 256, 0, stream>>>(x, xb, N * 256);
  transpose_w<<<dim3(2048 / 32, 256 / 32), 256, 0, stream>>>(W1, Wt1, 256, 2048);
  transpose_w<<<dim3(2048 / 32, 2048 / 32), 256, 0, stream>>>(W2, Wt2, 2048, 2048);
  transpose_w<<<dim3(1024 / 32, 2048 / 32), 256, 0, stream>>>(W3, Wt3, 2048, 1024);

  dim3 blk(256);
  int mb = (N + 127) / 128;

  // layer 1: Fin=256, Fout=2048
  gemm_bf16<<<dim3(2048 / 128, mb), blk, 0, stream>>>((const ushort*)xb, (const ushort*)Wt1, bufA, N, 256, 2048);
  compute_al<<<N, blk, 0, stream>>>(bufA, a1s, a1d, als, ald, 2048);
  aggregate<8, true><<<N, blk, 0, stream>>>(bufA, als, ald, rowptr, eidx, b1, hbf, 2048);

  // layer 2: Fin=2048, Fout=2048
  gemm_bf16<<<dim3(2048 / 128, mb), blk, 0, stream>>>((const ushort*)hbf, (const ushort*)Wt2, bufA, N, 2048, 2048);
  compute_al<<<N, blk, 0, stream>>>(bufA, a2s, a2d, als, ald, 2048);
  aggregate<8, true><<<N, blk, 0, stream>>>(bufA, als, ald, rowptr, eidx, b2, hbf, 2048);

  // layer 3: Fin=2048, Fout=1024
  gemm_bf16<<<dim3(1024 / 128, mb), blk, 0, stream>>>((const ushort*)hbf, (const ushort*)Wt3, bufA, N, 2048, 1024);
  compute_al<<<N, blk, 0, stream>>>(bufA, a3s, a3d, als, ald, 1024);
  // reuse hbf region as f32 output of layer 3 (10000*1024*4 == 10000*2048*2 bytes)
  float* hf32 = (float*)hbf;
  aggregate<4, false><<<N, blk, 0, stream>>>(bufA, als, ald, rowptr, eidx, b3, hf32, 1024);

  normalize_kernel<<<N, blk, 0, stream>>>(hf32, (float*)d_out, 1024);
}

// Round 5
// 477.287 us; speedup vs baseline: 6.7378x; 1.3291x over previous
//
#include <hip/hip_runtime.h>
#include <hip/hip_bf16.h>
#include <math.h>

// ---------------------------------------------------------------------------
// 3-layer GAT forward. Round 5:
//  - GEMM: m97 structure — global_load_lds width=16, linear LDS [128][32].
//  - Layers 1-2: xw kept bf16; aggregate + compute_al read bf16 (halves the
//    dominant edge-gather traffic). Layer 3 stays f32 for error headroom.
// ---------------------------------------------------------------------------

typedef __attribute__((ext_vector_type(8))) short short8;
typedef __attribute__((ext_vector_type(4))) float f32x4;

#define GLOAD_LDS16(g, l)                                            \
  __builtin_amdgcn_global_load_lds(                                  \
      (const __attribute__((address_space(1))) void*)(g),            \
      (__attribute__((address_space(3))) void*)(l), 16, 0, 0)

__device__ __forceinline__ float bf16_to_f32(ushort u) {
  return __uint_as_float(((unsigned int)u) << 16);
}

__device__ __forceinline__ float block_reduce_sum_bcast(float v) {
#pragma unroll
  for (int off = 32; off > 0; off >>= 1) v += __shfl_down(v, off, 64);
  __shared__ float tmp[4];
  __shared__ float res;
  int lane = threadIdx.x & 63, w = threadIdx.x >> 6;
  if (lane == 0) tmp[w] = v;
  __syncthreads();
  if (threadIdx.x == 0) res = tmp[0] + tmp[1] + tmp[2] + tmp[3];
  __syncthreads();
  float out = res;
  __syncthreads();
  return out;
}

__device__ __forceinline__ float block_reduce_max_bcast(float v) {
#pragma unroll
  for (int off = 32; off > 0; off >>= 1) v = fmaxf(v, __shfl_down(v, off, 64));
  __shared__ float tmpm[4];
  __shared__ float resm;
  int lane = threadIdx.x & 63, w = threadIdx.x >> 6;
  if (lane == 0) tmpm[w] = v;
  __syncthreads();
  if (threadIdx.x == 0) resm = fmaxf(fmaxf(tmpm[0], tmpm[1]), fmaxf(tmpm[2], tmpm[3]));
  __syncthreads();
  float out = resm;
  __syncthreads();
  return out;
}

// ---------------------------------------------------------------------------
// edge_index dtype detection (int64 vs int32), kept for robustness.
// ---------------------------------------------------------------------------
__global__ void detect_kernel(const int* __restrict__ ei32, int* __restrict__ flag) {
  __shared__ int cnt;
  if (threadIdx.x == 0) cnt = 0;
  __syncthreads();
  int zeros = 0;
  for (int i = threadIdx.x; i < 1024; i += 256) {
    if (ei32[2 * i + 1] == 0) zeros++;
  }
  atomicAdd(&cnt, zeros);
  __syncthreads();
  if (threadIdx.x == 0) *flag = (cnt > 900) ? 1 : 0;
}

__global__ void convert_kernel(const void* __restrict__ ei, const int* __restrict__ flag,
                               int E, int* __restrict__ src, int* __restrict__ dst) {
  int i = blockIdx.x * blockDim.x + threadIdx.x;
  if (i >= E) return;
  if (*flag) {
    const long long* p = (const long long*)ei;
    src[i] = (int)p[i];
    dst[i] = (int)p[E + i];
  } else {
    const int* p = (const int*)ei;
    src[i] = p[i];
    dst[i] = p[E + i];
  }
}

// ---------------------------------------------------------------------------
__global__ __launch_bounds__(256) void convert_f32_bf16(const float* __restrict__ in,
                                                        __hip_bfloat16* __restrict__ out,
                                                        int n) {
  int i = blockIdx.x * blockDim.x + threadIdx.x;
  if (i < n) out[i] = __float2bfloat16(in[i]);
}

// ---------------------------------------------------------------------------
// Transpose W [K][N] f32 -> Wt [N][K] bf16.  32x32 tiles, 256 threads.
// ---------------------------------------------------------------------------
__global__ __launch_bounds__(256) void transpose_w(const float* __restrict__ W,
                                                   __hip_bfloat16* __restrict__ Wt,
                                                   int K, int Nout) {
  __shared__ float t[32][33];
  int tx = threadIdx.x & 31, ty = threadIdx.x >> 5;  // 32 x 8
  int n0 = blockIdx.x * 32, k0 = blockIdx.y * 32;
#pragma unroll
  for (int i = 0; i < 4; ++i) {
    int k = k0 + ty + i * 8;
    t[ty + i * 8][tx] = W[(size_t)k * Nout + n0 + tx];
  }
  __syncthreads();
#pragma unroll
  for (int i = 0; i < 4; ++i) {
    int n = n0 + ty + i * 8;
    Wt[(size_t)n * K + k0 + tx] = __float2bfloat16(t[tx][ty + i * 8]);
  }
}

// ---------------------------------------------------------------------------
// C[M][Nout] = A[M][K](bf16) @ Bt[Nout][K](bf16)^T.  128x128 tile, BK=32,
// 4 waves, mfma_f32_16x16x32_bf16, global_load_lds staging (m97 structure).
// BF16OUT: write bf16 (feeds next stage) or f32.
// ---------------------------------------------------------------------------
template <bool BF16OUT>
__global__ __launch_bounds__(256) void gemm_bf16(const ushort* __restrict__ A,
                                                 const ushort* __restrict__ Bt,
                                                 void* __restrict__ C,
                                                 int M, int K, int Nout) {
  __shared__ ushort As[128 * 32];
  __shared__ ushort Bs[128 * 32];
  int tid = threadIdx.x;
  int lane = tid & 63, w = tid >> 6;
  int wr = (w >> 1) * 64, wc = (w & 1) * 64;
  int l15 = lane & 15, lhi = lane >> 4;
  int row0 = blockIdx.y * 128, col0 = blockIdx.x * 128;

  // staging geometry: each wave covers 32 rows (2 instrs x 16 rows),
  // lane l -> row (l>>2), 16-byte chunk (l&3) within the 64-byte row.
  int srow = w * 32 + (lane >> 2);
  int scol = (lane & 3) * 8;  // ushort offset
  ushort* la0 = &As[(w * 32) * 32];
  ushort* la1 = &As[(w * 32 + 16) * 32];
  ushort* lb0 = &Bs[(w * 32) * 32];
  ushort* lb1 = &Bs[(w * 32 + 16) * 32];
  // clamp A rows (garbage rows masked at C-write); B always in range.
  int ar0 = min(row0 + srow, M - 1);
  int ar1 = min(row0 + srow + 16, M - 1);
  const ushort* gb0 = Bt + (size_t)(col0 + srow) * K + scol;
  const ushort* gb1 = Bt + (size_t)(col0 + srow + 16) * K + scol;
  const ushort* ga0 = A + (size_t)ar0 * K + scol;
  const ushort* ga1 = A + (size_t)ar1 * K + scol;

  f32x4 acc[4][4] = {};

  for (int k0 = 0; k0 < K; k0 += 32) {
    GLOAD_LDS16(ga0 + k0, la0);
    GLOAD_LDS16(ga1 + k0, la1);
    GLOAD_LDS16(gb0 + k0, lb0);
    GLOAD_LDS16(gb1 + k0, lb1);
    __syncthreads();
    short8 af[4], bfr[4];
#pragma unroll
    for (int m = 0; m < 4; ++m)
      af[m] = *(const short8*)(&As[(wr + m * 16 + l15) * 32 + lhi * 8]);
#pragma unroll
    for (int n = 0; n < 4; ++n)
      bfr[n] = *(const short8*)(&Bs[(wc + n * 16 + l15) * 32 + lhi * 8]);
#pragma unroll
    for (int m = 0; m < 4; ++m)
#pragma unroll
      for (int n = 0; n < 4; ++n)
        acc[m][n] = __builtin_amdgcn_mfma_f32_16x16x32_bf16(af[m], bfr[n], acc[m][n], 0, 0, 0);
    __syncthreads();
  }

  // epilogue: D mapping col=lane&15, row=(lane>>4)*4+reg
#pragma unroll
  for (int m = 0; m < 4; ++m) {
#pragma unroll
    for (int v = 0; v < 4; ++v) {
      int r = row0 + wr + m * 16 + lhi * 4 + v;
      if (r < M) {
#pragma unroll
        for (int n = 0; n < 4; ++n) {
          size_t idx = (size_t)r * Nout + col0 + wc + n * 16 + l15;
          if (BF16OUT)
            ((__hip_bfloat16*)C)[idx] = __float2bfloat16(acc[m][n][v]);
          else
            ((float*)C)[idx] = acc[m][n][v];
        }
      }
    }
  }
}

// ---------------------------------------------------------------------------
// al_src[n] = dot(xw[n,:], a_s); al_dst[n] = dot(xw[n,:], a_d)
// BF16IN: xw is bf16 (F==2048) else f32.
// ---------------------------------------------------------------------------
template <bool BF16IN>
__global__ __launch_bounds__(256) void compute_al(const void* __restrict__ xw,
                                                  const float* __restrict__ a_s,
                                                  const float* __restrict__ a_d,
                                                  float* __restrict__ als,
                                                  float* __restrict__ ald, int F) {
  int n = blockIdx.x;
  float s1 = 0.f, s2 = 0.f;
  if (BF16IN) {
    const ushort* row = (const ushort*)xw + (size_t)n * F;
    int base = threadIdx.x * 8;  // 256*8 == 2048
    short8 v = *(const short8*)(row + base);
#pragma unroll
    for (int j = 0; j < 8; ++j) {
      float f = bf16_to_f32((ushort)v[j]);
      s1 += f * a_s[base + j];
      s2 += f * a_d[base + j];
    }
  } else {
    const float* row = (const float*)xw + (size_t)n * F;
    for (int f = threadIdx.x; f < F; f += 256) {
      float v = row[f];
      s1 += v * a_s[f];
      s2 += v * a_d[f];
    }
  }
  float r1 = block_reduce_sum_bcast(s1);
  float r2 = block_reduce_sum_bcast(s2);
  if (threadIdx.x == 0) {
    als[n] = r1;
    ald[n] = r2;
  }
}

// ---------------------------------------------------------------------------
// CSR build
// ---------------------------------------------------------------------------
__global__ void count_kernel(const int* __restrict__ dst, int* __restrict__ counts, int E) {
  int i = blockIdx.x * blockDim.x + threadIdx.x;
  if (i < E) atomicAdd(&counts[dst[i]], 1);
}

__global__ __launch_bounds__(1024) void scan_kernel(const int* __restrict__ counts,
                                                    int* __restrict__ rowptr,
                                                    int* __restrict__ cursor, int Nn) {
  __shared__ int part[1024];
  int tid = threadIdx.x;
  int chunk = (Nn + 1023) / 1024;
  int base = tid * chunk;
  int s = 0;
  for (int i = 0; i < chunk; ++i) {
    int idx = base + i;
    if (idx < Nn) s += counts[idx];
  }
  part[tid] = s;
  __syncthreads();
  for (int off = 1; off < 1024; off <<= 1) {
    int v = 0;
    if (tid >= off) v = part[tid - off];
    __syncthreads();
    if (tid >= off) part[tid] += v;
    __syncthreads();
  }
  int run = (tid == 0) ? 0 : part[tid - 1];
  for (int i = 0; i < chunk; ++i) {
    int idx = base + i;
    if (idx < Nn) {
      rowptr[idx] = run;
      cursor[idx] = run;
      run += counts[idx];
    }
  }
  if (tid == 1023) rowptr[Nn] = part[1023];
}

__global__ void fill_kernel(const int* __restrict__ src, const int* __restrict__ dst,
                            int* __restrict__ cursor, int* __restrict__ eidx, int E) {
  int i = blockIdx.x * blockDim.x + threadIdx.x;
  if (i < E) {
    int pos = atomicAdd(&cursor[dst[i]], 1);
    eidx[pos] = src[i];
  }
}

// ---------------------------------------------------------------------------
// Per-dst-node softmax attention + weighted gather + bias + ReLU.
// BF16IN: xw rows are bf16 (F==2048, uint-packed pair loads).
// BF16OUT: write bf16 (next layer GEMM input) or f32.
// ---------------------------------------------------------------------------
template <int FPT, bool BF16IN, bool BF16OUT>
__global__ __launch_bounds__(256) void aggregate(const void* __restrict__ xw,
                                                 const float* __restrict__ als,
                                                 const float* __restrict__ ald,
                                                 const int* __restrict__ rowptr,
                                                 const int* __restrict__ eidx,
                                                 const float* __restrict__ bias,
                                                 void* __restrict__ out, int F) {
  int n = blockIdx.x;
  int tid = threadIdx.x;
  int beg = rowptr[n], end = rowptr[n + 1];
  int deg = end - beg;
  float aldn = ald[n];

  float lm = -INFINITY;
  for (int j = tid; j < deg; j += 256) {
    int s = eidx[beg + j];
    float e = als[s] + aldn;
    e = (e > 0.f) ? e : 0.2f * e;
    lm = fmaxf(lm, e);
  }
  if (tid == 0) {
    float e = als[n] + aldn;
    e = (e > 0.f) ? e : 0.2f * e;
    lm = fmaxf(lm, e);
  }
  float m = block_reduce_max_bcast(lm);

  float ls = 0.f;
  for (int j = tid; j < deg; j += 256) {
    int s = eidx[beg + j];
    float e = als[s] + aldn;
    e = (e > 0.f) ? e : 0.2f * e;
    ls += expf(e - m);
  }
  if (tid == 0) {
    float e = als[n] + aldn;
    e = (e > 0.f) ? e : 0.2f * e;
    ls += expf(e - m);
  }
  float denom = block_reduce_sum_bcast(ls) + 1e-16f;
  float inv_denom = 1.f / denom;

  float acc[FPT];
#pragma unroll
  for (int i = 0; i < FPT; ++i) acc[i] = 0.f;

  __shared__ float alpha_sh[256];
  __shared__ int src_sh[256];
  int total = deg + 1;
  for (int c0 = 0; c0 < total; c0 += 256) {
    int j = c0 + tid;
    if (j < total) {
      int s = (j < deg) ? eidx[beg + j] : n;
      float e = als[s] + aldn;
      e = (e > 0.f) ? e : 0.2f * e;
      alpha_sh[tid] = expf(e - m) * inv_denom;
      src_sh[tid] = s;
    }
    __syncthreads();
    int cn = min(256, total - c0);
    for (int jj = 0; jj < cn; ++jj) {
      float al = alpha_sh[jj];
      if (BF16IN) {
        const ushort* row = (const ushort*)xw + (size_t)src_sh[jj] * F;
#pragma unroll
        for (int i = 0; i < FPT / 2; ++i) {
          unsigned int u = *(const unsigned int*)(row + tid * 2 + i * 512);
          acc[2 * i]     += al * __uint_as_float((u & 0xffffu) << 16);
          acc[2 * i + 1] += al * __uint_as_float(u & 0xffff0000u);
        }
      } else {
        const float* row = (const float*)xw + (size_t)src_sh[jj] * F;
#pragma unroll
        for (int i = 0; i < FPT; ++i) acc[i] += al * row[tid + i * 256];
      }
    }
    __syncthreads();
  }

#pragma unroll
  for (int i = 0; i < FPT; ++i) {
    int col = BF16IN ? (tid * 2 + (i >> 1) * 512 + (i & 1)) : (tid + i * 256);
    float v = fmaxf(acc[i] + bias[col], 0.f);
    size_t idx = (size_t)n * F + col;
    if (BF16OUT)
      ((__hip_bfloat16*)out)[idx] = __float2bfloat16(v);
    else
      ((float*)out)[idx] = v;
  }
}

// ---------------------------------------------------------------------------
// Row L2 normalize (eps 1e-12), write f32.
// ---------------------------------------------------------------------------
__global__ __launch_bounds__(256) void normalize_kernel(const float* __restrict__ h,
                                                        float* __restrict__ out,
                                                        int F) {
  int n = blockIdx.x;
  const float* row = h + (size_t)n * F;
  float ss = 0.f;
  for (int f = threadIdx.x; f < F; f += 256) {
    float v = row[f];
    ss += v * v;
  }
  float tot = block_reduce_sum_bcast(ss);
  float inv = 1.f / fmaxf(sqrtf(tot), 1e-12f);
  for (int f = threadIdx.x; f < F; f += 256) {
    out[(size_t)n * F + f] = row[f] * inv;
  }
}

// ---------------------------------------------------------------------------
extern "C" void kernel_launch(void* const* d_in, const int* in_sizes, int n_in,
                              void* d_out, int out_size, void* d_ws, size_t ws_size,
                              hipStream_t stream) {
  const float* x   = (const float*)d_in[0];
  const void*  ei  = d_in[1];
  const float* W1  = (const float*)d_in[2];
  const float* W2  = (const float*)d_in[3];
  const float* W3  = (const float*)d_in[4];
  const float* a1s = (const float*)d_in[5];
  const float* a1d = (const float*)d_in[6];
  const float* a2s = (const float*)d_in[7];
  const float* a2d = (const float*)d_in[8];
  const float* a3s = (const float*)d_in[9];
  const float* a3d = (const float*)d_in[10];
  const float* b1  = (const float*)d_in[11];
  const float* b2  = (const float*)d_in[12];
  const float* b3  = (const float*)d_in[13];

  const int N = in_sizes[0] / 256;  // 10000
  const int E = in_sizes[1] / 2;    // 80000

  char* ws = (char*)d_ws;
  size_t off = 0;
  auto alloc = [&](size_t bytes) -> void* {
    void* p = ws + off;
    off += (bytes + 255) & ~(size_t)255;
    return p;
  };
  ushort* xwb = (ushort*)alloc((size_t)N * 2048 * 2);   // GEMM out bf16 (L1,L2); f32 final agg out (L3)
  ushort* hbf = (ushort*)alloc((size_t)N * 2048 * 2);   // aggregated activations bf16
  float* bufA = (float*)alloc((size_t)N * 1024 * 4);    // L3 GEMM out f32
  __hip_bfloat16* xb  = (__hip_bfloat16*)alloc((size_t)N * 256 * 2);
  __hip_bfloat16* Wt1 = (__hip_bfloat16*)alloc((size_t)2048 * 256 * 2);
  __hip_bfloat16* Wt2 = (__hip_bfloat16*)alloc((size_t)2048 * 2048 * 2);
  __hip_bfloat16* Wt3 = (__hip_bfloat16*)alloc((size_t)1024 * 2048 * 2);
  float* als   = (float*)alloc((size_t)N * 4);
  float* ald   = (float*)alloc((size_t)N * 4);
  int* counts  = (int*)alloc((size_t)N * 4);
  int* rowptr  = (int*)alloc((size_t)(N + 1) * 4);
  int* cursor  = (int*)alloc((size_t)N * 4);
  int* eidx    = (int*)alloc((size_t)E * 4);
  int* src32   = (int*)alloc((size_t)E * 4);
  int* dst32   = (int*)alloc((size_t)E * 4);
  int* flag    = (int*)alloc(256);

  // edge_index dtype detect + convert; CSR build (by dst)
  detect_kernel<<<1, 256, 0, stream>>>((const int*)ei, flag);
  convert_kernel<<<(E + 255) / 256, 256, 0, stream>>>(ei, flag, E, src32, dst32);
  hipMemsetAsync(counts, 0, (size_t)N * 4, stream);
  count_kernel<<<(E + 255) / 256, 256, 0, stream>>>(dst32, counts, E);
  scan_kernel<<<1, 1024, 0, stream>>>(counts, rowptr, cursor, N);
  fill_kernel<<<(E + 255) / 256, 256, 0, stream>>>(src32, dst32, cursor, eidx, E);

  // bf16 prep
  convert_f32_bf16<<<(N * 256 + 255) / 256, 256, 0, stream>>>(x, xb, N * 256);
  transpose_w<<<dim3(2048 / 32, 256 / 32), 256, 0, stream>>>(W1, Wt1, 256, 2048);
  transpose_w<<<dim3(2048 / 32, 2048 / 32), 256, 0, stream>>>(W2, Wt2, 2048, 2048);
  transpose_w<<<dim3(1024 / 32, 2048 / 32), 256, 0, stream>>>(W3, Wt3, 2048, 1024);

  dim3 blk(256);
  int mb = (N + 127) / 128;

  // layer 1: Fin=256, Fout=2048   (bf16 xw path)
  gemm_bf16<true><<<dim3(2048 / 128, mb), blk, 0, stream>>>((const ushort*)xb, (const ushort*)Wt1, xwb, N, 256, 2048);
  compute_al<true><<<N, blk, 0, stream>>>(xwb, a1s, a1d, als, ald, 2048);
  aggregate<8, true, true><<<N, blk, 0, stream>>>(xwb, als, ald, rowptr, eidx, b1, hbf, 2048);

  // layer 2: Fin=2048, Fout=2048  (bf16 xw path)
  gemm_bf16<true><<<dim3(2048 / 128, mb), blk, 0, stream>>>(hbf, (const ushort*)Wt2, xwb, N, 2048, 2048);
  compute_al<true><<<N, blk, 0, stream>>>(xwb, a2s, a2d, als, ald, 2048);
  aggregate<8, true, true><<<N, blk, 0, stream>>>(xwb, als, ald, rowptr, eidx, b2, hbf, 2048);

  // layer 3: Fin=2048, Fout=1024  (f32 path for error headroom)
  gemm_bf16<false><<<dim3(1024 / 128, mb), blk, 0, stream>>>(hbf, (const ushort*)Wt3, bufA, N, 2048, 1024);
  compute_al<false><<<N, blk, 0, stream>>>(bufA, a3s, a3d, als, ald, 1024);
  float* hf32 = (float*)xwb;  // xwb free after L2 GEMM consumed... (L3 reads hbf) — reuse as f32 out
  aggregate<4, false, false><<<N, blk, 0, stream>>>(bufA, als, ald, rowptr, eidx, b3, hf32, 1024);

  normalize_kernel<<<N, blk, 0, stream>>>(hf32, (float*)d_out, 1024);
}

// Round 6
// 474.617 us; speedup vs baseline: 6.7757x; 1.0056x over previous
//
#include <hip/hip_runtime.h>
#include <hip/hip_bf16.h>
#include <math.h>

// ---------------------------------------------------------------------------
// 3-layer GAT forward. Round 6: GEMM -> 256x256 8-wave deep-pipelined MFMA
// kernel (T2 st_16x32 swizzle + T3/T4 counted vmcnt + T5 setprio).
// Aggregation / softmax unchanged from R5 (passed).
// ---------------------------------------------------------------------------

typedef __attribute__((ext_vector_type(8))) short short8;
typedef __attribute__((ext_vector_type(4))) float f32x4;

#define GLOAD_LDS16(g, l)                                            \
  __builtin_amdgcn_global_load_lds(                                  \
      (const __attribute__((address_space(1))) void*)(g),            \
      (__attribute__((address_space(3))) void*)(l), 16, 0, 0)

__device__ __forceinline__ float bf16_to_f32(ushort u) {
  return __uint_as_float(((unsigned int)u) << 16);
}

__device__ __forceinline__ float block_reduce_sum_bcast(float v) {
#pragma unroll
  for (int off = 32; off > 0; off >>= 1) v += __shfl_down(v, off, 64);
  __shared__ float tmp[4];
  __shared__ float res;
  int lane = threadIdx.x & 63, w = threadIdx.x >> 6;
  if (lane == 0) tmp[w] = v;
  __syncthreads();
  if (threadIdx.x == 0) res = tmp[0] + tmp[1] + tmp[2] + tmp[3];
  __syncthreads();
  float out = res;
  __syncthreads();
  return out;
}

__device__ __forceinline__ float block_reduce_max_bcast(float v) {
#pragma unroll
  for (int off = 32; off > 0; off >>= 1) v = fmaxf(v, __shfl_down(v, off, 64));
  __shared__ float tmpm[4];
  __shared__ float resm;
  int lane = threadIdx.x & 63, w = threadIdx.x >> 6;
  if (lane == 0) tmpm[w] = v;
  __syncthreads();
  if (threadIdx.x == 0) resm = fmaxf(fmaxf(tmpm[0], tmpm[1]), fmaxf(tmpm[2], tmpm[3]));
  __syncthreads();
  float out = resm;
  __syncthreads();
  return out;
}

// ---------------------------------------------------------------------------
// edge_index dtype detection (int64 vs int32), kept for robustness.
// ---------------------------------------------------------------------------
__global__ void detect_kernel(const int* __restrict__ ei32, int* __restrict__ flag) {
  __shared__ int cnt;
  if (threadIdx.x == 0) cnt = 0;
  __syncthreads();
  int zeros = 0;
  for (int i = threadIdx.x; i < 1024; i += 256) {
    if (ei32[2 * i + 1] == 0) zeros++;
  }
  atomicAdd(&cnt, zeros);
  __syncthreads();
  if (threadIdx.x == 0) *flag = (cnt > 900) ? 1 : 0;
}

__global__ void convert_kernel(const void* __restrict__ ei, const int* __restrict__ flag,
                               int E, int* __restrict__ src, int* __restrict__ dst) {
  int i = blockIdx.x * blockDim.x + threadIdx.x;
  if (i >= E) return;
  if (*flag) {
    const long long* p = (const long long*)ei;
    src[i] = (int)p[i];
    dst[i] = (int)p[E + i];
  } else {
    const int* p = (const int*)ei;
    src[i] = p[i];
    dst[i] = p[E + i];
  }
}

// ---------------------------------------------------------------------------
__global__ __launch_bounds__(256) void convert_f32_bf16(const float* __restrict__ in,
                                                        __hip_bfloat16* __restrict__ out,
                                                        int n) {
  int i = blockIdx.x * blockDim.x + threadIdx.x;
  if (i < n) out[i] = __float2bfloat16(in[i]);
}

// ---------------------------------------------------------------------------
// Transpose W [K][N] f32 -> Wt [N][K] bf16.  32x32 tiles, 256 threads.
// ---------------------------------------------------------------------------
__global__ __launch_bounds__(256) void transpose_w(const float* __restrict__ W,
                                                   __hip_bfloat16* __restrict__ Wt,
                                                   int K, int Nout) {
  __shared__ float t[32][33];
  int tx = threadIdx.x & 31, ty = threadIdx.x >> 5;  // 32 x 8
  int n0 = blockIdx.x * 32, k0 = blockIdx.y * 32;
#pragma unroll
  for (int i = 0; i < 4; ++i) {
    int k = k0 + ty + i * 8;
    t[ty + i * 8][tx] = W[(size_t)k * Nout + n0 + tx];
  }
  __syncthreads();
#pragma unroll
  for (int i = 0; i < 4; ++i) {
    int n = n0 + ty + i * 8;
    Wt[(size_t)n * K + k0 + tx] = __float2bfloat16(t[tx][ty + i * 8]);
  }
}

// ---------------------------------------------------------------------------
// C[M][Nout] = A[M][K](bf16) @ Bt[Nout][K](bf16)^T.
// 256x256 tile, BK=64, 512 threads (8 waves 2x4), double-buffered 128 KiB LDS,
// st_16x32 swizzle (write-side: pre-swizzled global src; read-side: swizzled
// ds_read chunk), counted vmcnt(4) pipeline (never 0 in main loop), setprio.
// LDS layout (ushort units): buf b: A subtile(sr,sc) at b*32768+(sr*2+sc)*512,
// B subtile(sn,sc) at b*32768+16384+(sn*2+sc)*512. Subtile = 16 rows x 32 cols.
// ---------------------------------------------------------------------------
template <bool BF16OUT>
__global__ __launch_bounds__(512, 2) void gemm256(const ushort* __restrict__ A,
                                                  const ushort* __restrict__ Bt,
                                                  void* __restrict__ C,
                                                  int M, int K, int Nout) {
  extern __shared__ ushort lds[];
  const int tid = threadIdx.x;
  const int l = tid & 63, w = tid >> 6;
  const int wm = w >> 2, wn = w & 3;
  const int l15 = l & 15, lhi = l >> 4;
  const int row0 = blockIdx.y * 256, col0 = blockIdx.x * 256;
  // write-side swizzle: lane l fills subtile byte l*16; fetches global chunk
  // c8sw = (l&3) ^ (((l>>5)&1)<<1) of row (l>>2).
  const int c8sw = (l & 3) ^ (((l >> 5) & 1) << 1);
  const int lrow = l >> 2;
  // read-side swizzle: logical (row=l15, chunk=lhi) lives at chunk lhi^((l15>>3)&1)<<1
  const int chsw = lhi ^ (((l15 >> 3) & 1) << 1);
  const int rd_off = l15 * 32 + chsw * 8;  // ushort units within subtile

  // per-thread global stage pointers: ga[sc][j] / gb[sc][j]
  const ushort* ga[2][2];
  const ushort* gb[2][2];
  const int sA0 = wm * 8 + wn * 2;                        // A subtile-row base staged by this wave
  const int sB0 = (wn >> 1) * 8 + (wm * 2 + (wn & 1)) * 2;  // B subtile-row base
#pragma unroll
  for (int sc = 0; sc < 2; ++sc) {
#pragma unroll
    for (int j = 0; j < 2; ++j) {
      int ar = min(row0 + (sA0 + j) * 16 + lrow, M - 1);  // clamp; masked at C-write
      ga[sc][j] = A + (size_t)ar * K + sc * 32 + c8sw * 8;
      gb[sc][j] = Bt + (size_t)(col0 + (sB0 + j) * 16 + lrow) * K + sc * 32 + c8sw * 8;
    }
  }

#define STAGE_A(nb, kn, sc)                                                       \
  do {                                                                            \
    GLOAD_LDS16(ga[sc][0] + (kn), &lds[(nb)*32768 + ((sA0 + 0) * 2 + (sc)) * 512]); \
    GLOAD_LDS16(ga[sc][1] + (kn), &lds[(nb)*32768 + ((sA0 + 1) * 2 + (sc)) * 512]); \
  } while (0)
#define STAGE_B(nb, kn, sc)                                                       \
  do {                                                                            \
    GLOAD_LDS16(gb[sc][0] + (kn), &lds[(nb)*32768 + 16384 + ((sB0 + 0) * 2 + (sc)) * 512]); \
    GLOAD_LDS16(gb[sc][1] + (kn), &lds[(nb)*32768 + 16384 + ((sB0 + 1) * 2 + (sc)) * 512]); \
  } while (0)

  f32x4 acc[8][4] = {};

#define PHASE(cur, mh, kk, STAGE_STMT)                                            \
  do {                                                                            \
    short8 af[4], bf[4];                                                          \
    const ushort* Ab = &lds[(cur)*32768];                                         \
    const ushort* Bb = &lds[(cur)*32768 + 16384];                                 \
    _Pragma("unroll") for (int m = 0; m < 4; ++m)                                 \
        af[m] = *(const short8*)(Ab + ((wm * 8 + (mh)*4 + m) * 2 + (kk)) * 512 + rd_off); \
    _Pragma("unroll") for (int n = 0; n < 4; ++n)                                 \
        bf[n] = *(const short8*)(Bb + ((wn * 4 + n) * 2 + (kk)) * 512 + rd_off);  \
    STAGE_STMT;                                                                   \
    asm volatile("s_waitcnt vmcnt(4)" ::: "memory");                              \
    __builtin_amdgcn_s_barrier();                                                 \
    __builtin_amdgcn_s_setprio(1);                                                \
    _Pragma("unroll") for (int m = 0; m < 4; ++m)                                 \
        _Pragma("unroll") for (int n = 0; n < 4; ++n)                             \
            acc[(mh)*4 + m][n] = __builtin_amdgcn_mfma_f32_16x16x32_bf16(         \
                af[m], bf[n], acc[(mh)*4 + m][n], 0, 0, 0);                       \
    __builtin_amdgcn_s_setprio(0);                                                \
    __builtin_amdgcn_s_barrier();                                                 \
  } while (0)

  // prologue: stage tile 0 fully, drain, barrier
  STAGE_A(0, 0, 0);
  STAGE_B(0, 0, 0);
  STAGE_A(0, 0, 1);
  STAGE_B(0, 0, 1);
  asm volatile("s_waitcnt vmcnt(0)" ::: "memory");
  __builtin_amdgcn_s_barrier();

  const int nt = K >> 6;
  int cur = 0;
  for (int t = 0; t < nt; ++t) {
    const int kn = (t + 1) << 6;  // ushort offset for next K-tile
    const bool pf = (t + 1) < nt;
    const int nb = cur ^ 1;
    // staged-at-phase-g data is readable from phase g+3 (vmcnt(4) at every
    // barrier retires the 2-loads/phase group issued 2 phases earlier):
    // A-k0: g=0 -> read @4 OK; B-k0: g=1 -> read @4 OK (exact);
    // A-k1: g=2 -> read @6 OK; B-k1: g=3 -> read @6 OK (exact).
    PHASE(cur, 0, 0, if (pf) STAGE_A(nb, kn, 0));
    PHASE(cur, 1, 0, if (pf) STAGE_B(nb, kn, 0));
    PHASE(cur, 0, 1, if (pf) STAGE_A(nb, kn, 1));
    PHASE(cur, 1, 1, if (pf) STAGE_B(nb, kn, 1));
    cur ^= 1;
  }

  // epilogue: D mapping col=lane&15, row=(lane>>4)*4+reg
#pragma unroll
  for (int mi = 0; mi < 8; ++mi) {
#pragma unroll
    for (int v = 0; v < 4; ++v) {
      int r = row0 + wm * 128 + mi * 16 + lhi * 4 + v;
      if (r < M) {
#pragma unroll
        for (int n = 0; n < 4; ++n) {
          size_t idx = (size_t)r * Nout + col0 + wn * 64 + n * 16 + l15;
          if (BF16OUT)
            ((__hip_bfloat16*)C)[idx] = __float2bfloat16(acc[mi][n][v]);
          else
            ((float*)C)[idx] = acc[mi][n][v];
        }
      }
    }
  }
#undef PHASE
#undef STAGE_A
#undef STAGE_B
}

// ---------------------------------------------------------------------------
// al_src[n] = dot(xw[n,:], a_s); al_dst[n] = dot(xw[n,:], a_d)
// ---------------------------------------------------------------------------
template <bool BF16IN>
__global__ __launch_bounds__(256) void compute_al(const void* __restrict__ xw,
                                                  const float* __restrict__ a_s,
                                                  const float* __restrict__ a_d,
                                                  float* __restrict__ als,
                                                  float* __restrict__ ald, int F) {
  int n = blockIdx.x;
  float s1 = 0.f, s2 = 0.f;
  if (BF16IN) {
    const ushort* row = (const ushort*)xw + (size_t)n * F;
    int base = threadIdx.x * 8;  // 256*8 == 2048
    short8 v = *(const short8*)(row + base);
#pragma unroll
    for (int j = 0; j < 8; ++j) {
      float f = bf16_to_f32((ushort)v[j]);
      s1 += f * a_s[base + j];
      s2 += f * a_d[base + j];
    }
  } else {
    const float* row = (const float*)xw + (size_t)n * F;
    for (int f = threadIdx.x; f < F; f += 256) {
      float v = row[f];
      s1 += v * a_s[f];
      s2 += v * a_d[f];
    }
  }
  float r1 = block_reduce_sum_bcast(s1);
  float r2 = block_reduce_sum_bcast(s2);
  if (threadIdx.x == 0) {
    als[n] = r1;
    ald[n] = r2;
  }
}

// ---------------------------------------------------------------------------
// CSR build
// ---------------------------------------------------------------------------
__global__ void count_kernel(const int* __restrict__ dst, int* __restrict__ counts, int E) {
  int i = blockIdx.x * blockDim.x + threadIdx.x;
  if (i < E) atomicAdd(&counts[dst[i]], 1);
}

__global__ __launch_bounds__(1024) void scan_kernel(const int* __restrict__ counts,
                                                    int* __restrict__ rowptr,
                                                    int* __restrict__ cursor, int Nn) {
  __shared__ int part[1024];
  int tid = threadIdx.x;
  int chunk = (Nn + 1023) / 1024;
  int base = tid * chunk;
  int s = 0;
  for (int i = 0; i < chunk; ++i) {
    int idx = base + i;
    if (idx < Nn) s += counts[idx];
  }
  part[tid] = s;
  __syncthreads();
  for (int off = 1; off < 1024; off <<= 1) {
    int v = 0;
    if (tid >= off) v = part[tid - off];
    __syncthreads();
    if (tid >= off) part[tid] += v;
    __syncthreads();
  }
  int run = (tid == 0) ? 0 : part[tid - 1];
  for (int i = 0; i < chunk; ++i) {
    int idx = base + i;
    if (idx < Nn) {
      rowptr[idx] = run;
      cursor[idx] = run;
      run += counts[idx];
    }
  }
  if (tid == 1023) rowptr[Nn] = part[1023];
}

__global__ void fill_kernel(const int* __restrict__ src, const int* __restrict__ dst,
                            int* __restrict__ cursor, int* __restrict__ eidx, int E) {
  int i = blockIdx.x * blockDim.x + threadIdx.x;
  if (i < E) {
    int pos = atomicAdd(&cursor[dst[i]], 1);
    eidx[pos] = src[i];
  }
}

// ---------------------------------------------------------------------------
// Per-dst-node softmax attention + weighted gather + bias + ReLU.
// ---------------------------------------------------------------------------
template <int FPT, bool BF16IN, bool BF16OUT>
__global__ __launch_bounds__(256) void aggregate(const void* __restrict__ xw,
                                                 const float* __restrict__ als,
                                                 const float* __restrict__ ald,
                                                 const int* __restrict__ rowptr,
                                                 const int* __restrict__ eidx,
                                                 const float* __restrict__ bias,
                                                 void* __restrict__ out, int F) {
  int n = blockIdx.x;
  int tid = threadIdx.x;
  int beg = rowptr[n], end = rowptr[n + 1];
  int deg = end - beg;
  float aldn = ald[n];

  float lm = -INFINITY;
  for (int j = tid; j < deg; j += 256) {
    int s = eidx[beg + j];
    float e = als[s] + aldn;
    e = (e > 0.f) ? e : 0.2f * e;
    lm = fmaxf(lm, e);
  }
  if (tid == 0) {
    float e = als[n] + aldn;
    e = (e > 0.f) ? e : 0.2f * e;
    lm = fmaxf(lm, e);
  }
  float m = block_reduce_max_bcast(lm);

  float ls = 0.f;
  for (int j = tid; j < deg; j += 256) {
    int s = eidx[beg + j];
    float e = als[s] + aldn;
    e = (e > 0.f) ? e : 0.2f * e;
    ls += expf(e - m);
  }
  if (tid == 0) {
    float e = als[n] + aldn;
    e = (e > 0.f) ? e : 0.2f * e;
    ls += expf(e - m);
  }
  float denom = block_reduce_sum_bcast(ls) + 1e-16f;
  float inv_denom = 1.f / denom;

  float acc[FPT];
#pragma unroll
  for (int i = 0; i < FPT; ++i) acc[i] = 0.f;

  __shared__ float alpha_sh[256];
  __shared__ int src_sh[256];
  int total = deg + 1;
  for (int c0 = 0; c0 < total; c0 += 256) {
    int j = c0 + tid;
    if (j < total) {
      int s = (j < deg) ? eidx[beg + j] : n;
      float e = als[s] + aldn;
      e = (e > 0.f) ? e : 0.2f * e;
      alpha_sh[tid] = expf(e - m) * inv_denom;
      src_sh[tid] = s;
    }
    __syncthreads();
    int cn = min(256, total - c0);
    for (int jj = 0; jj < cn; ++jj) {
      float al = alpha_sh[jj];
      if (BF16IN) {
        const ushort* row = (const ushort*)xw + (size_t)src_sh[jj] * F;
#pragma unroll
        for (int i = 0; i < FPT / 2; ++i) {
          unsigned int u = *(const unsigned int*)(row + tid * 2 + i * 512);
          acc[2 * i]     += al * __uint_as_float((u & 0xffffu) << 16);
          acc[2 * i + 1] += al * __uint_as_float(u & 0xffff0000u);
        }
      } else {
        const float* row = (const float*)xw + (size_t)src_sh[jj] * F;
#pragma unroll
        for (int i = 0; i < FPT; ++i) acc[i] += al * row[tid + i * 256];
      }
    }
    __syncthreads();
  }

#pragma unroll
  for (int i = 0; i < FPT; ++i) {
    int col = BF16IN ? (tid * 2 + (i >> 1) * 512 + (i & 1)) : (tid + i * 256);
    float v = fmaxf(acc[i] + bias[col], 0.f);
    size_t idx = (size_t)n * F + col;
    if (BF16OUT)
      ((__hip_bfloat16*)out)[idx] = __float2bfloat16(v);
    else
      ((float*)out)[idx] = v;
  }
}

// ---------------------------------------------------------------------------
// Row L2 normalize (eps 1e-12), write f32.
// ---------------------------------------------------------------------------
__global__ __launch_bounds__(256) void normalize_kernel(const float* __restrict__ h,
                                                        float* __restrict__ out,
                                                        int F) {
  int n = blockIdx.x;
  const float* row = h + (size_t)n * F;
  float ss = 0.f;
  for (int f = threadIdx.x; f < F; f += 256) {
    float v = row[f];
    ss += v * v;
  }
  float tot = block_reduce_sum_bcast(ss);
  float inv = 1.f / fmaxf(sqrtf(tot), 1e-12f);
  for (int f = threadIdx.x; f < F; f += 256) {
    out[(size_t)n * F + f] = row[f] * inv;
  }
}

// ---------------------------------------------------------------------------
extern "C" void kernel_launch(void* const* d_in, const int* in_sizes, int n_in,
                              void* d_out, int out_size, void* d_ws, size_t ws_size,
                              hipStream_t stream) {
  const float* x   = (const float*)d_in[0];
  const void*  ei  = d_in[1];
  const float* W1  = (const float*)d_in[2];
  const float* W2  = (const float*)d_in[3];
  const float* W3  = (const float*)d_in[4];
  const float* a1s = (const float*)d_in[5];
  const float* a1d = (const float*)d_in[6];
  const float* a2s = (const float*)d_in[7];
  const float* a2d = (const float*)d_in[8];
  const float* a3s = (const float*)d_in[9];
  const float* a3d = (const float*)d_in[10];
  const float* b1  = (const float*)d_in[11];
  const float* b2  = (const float*)d_in[12];
  const float* b3  = (const float*)d_in[13];

  const int N = in_sizes[0] / 256;  // 10000
  const int E = in_sizes[1] / 2;    // 80000

  char* ws = (char*)d_ws;
  size_t off = 0;
  auto alloc = [&](size_t bytes) -> void* {
    void* p = ws + off;
    off += (bytes + 255) & ~(size_t)255;
    return p;
  };
  ushort* xwb = (ushort*)alloc((size_t)N * 2048 * 2);   // GEMM out bf16 (L1,L2); f32 agg out (L3)
  ushort* hbf = (ushort*)alloc((size_t)N * 2048 * 2);   // aggregated activations bf16
  float* bufA = (float*)alloc((size_t)N * 1024 * 4);    // L3 GEMM out f32
  __hip_bfloat16* xb  = (__hip_bfloat16*)alloc((size_t)N * 256 * 2);
  __hip_bfloat16* Wt1 = (__hip_bfloat16*)alloc((size_t)2048 * 256 * 2);
  __hip_bfloat16* Wt2 = (__hip_bfloat16*)alloc((size_t)2048 * 2048 * 2);
  __hip_bfloat16* Wt3 = (__hip_bfloat16*)alloc((size_t)1024 * 2048 * 2);
  float* als   = (float*)alloc((size_t)N * 4);
  float* ald   = (float*)alloc((size_t)N * 4);
  int* counts  = (int*)alloc((size_t)N * 4);
  int* rowptr  = (int*)alloc((size_t)(N + 1) * 4);
  int* cursor  = (int*)alloc((size_t)N * 4);
  int* eidx    = (int*)alloc((size_t)E * 4);
  int* src32   = (int*)alloc((size_t)E * 4);
  int* dst32   = (int*)alloc((size_t)E * 4);
  int* flag    = (int*)alloc(256);

  // allow 128 KiB dynamic LDS for the GEMM kernels
  static bool attr_done = false;
  if (!attr_done) {
    hipFuncSetAttribute((const void*)gemm256<true>,
                        hipFuncAttributeMaxDynamicSharedMemorySize, 131072);
    hipFuncSetAttribute((const void*)gemm256<false>,
                        hipFuncAttributeMaxDynamicSharedMemorySize, 131072);
    attr_done = true;
  }

  // edge_index dtype detect + convert; CSR build (by dst)
  detect_kernel<<<1, 256, 0, stream>>>((const int*)ei, flag);
  convert_kernel<<<(E + 255) / 256, 256, 0, stream>>>(ei, flag, E, src32, dst32);
  hipMemsetAsync(counts, 0, (size_t)N * 4, stream);
  count_kernel<<<(E + 255) / 256, 256, 0, stream>>>(dst32, counts, E);
  scan_kernel<<<1, 1024, 0, stream>>>(counts, rowptr, cursor, N);
  fill_kernel<<<(E + 255) / 256, 256, 0, stream>>>(src32, dst32, cursor, eidx, E);

  // bf16 prep
  convert_f32_bf16<<<(N * 256 + 255) / 256, 256, 0, stream>>>(x, xb, N * 256);
  transpose_w<<<dim3(2048 / 32, 256 / 32), 256, 0, stream>>>(W1, Wt1, 256, 2048);
  transpose_w<<<dim3(2048 / 32, 2048 / 32), 256, 0, stream>>>(W2, Wt2, 2048, 2048);
  transpose_w<<<dim3(1024 / 32, 2048 / 32), 256, 0, stream>>>(W3, Wt3, 2048, 1024);

  dim3 blk(256);
  dim3 gblk(512);
  int mb = (N + 255) / 256;

  // layer 1: Fin=256, Fout=2048   (bf16 xw path)
  gemm256<true><<<dim3(2048 / 256, mb), gblk, 131072, stream>>>((const ushort*)xb, (const ushort*)Wt1, xwb, N, 256, 2048);
  compute_al<true><<<N, blk, 0, stream>>>(xwb, a1s, a1d, als, ald, 2048);
  aggregate<8, true, true><<<N, blk, 0, stream>>>(xwb, als, ald, rowptr, eidx, b1, hbf, 2048);

  // layer 2: Fin=2048, Fout=2048  (bf16 xw path)
  gemm256<true><<<dim3(2048 / 256, mb), gblk, 131072, stream>>>(hbf, (const ushort*)Wt2, xwb, N, 2048, 2048);
  compute_al<true><<<N, blk, 0, stream>>>(xwb, a2s, a2d, als, ald, 2048);
  aggregate<8, true, true><<<N, blk, 0, stream>>>(xwb, als, ald, rowptr, eidx, b2, hbf, 2048);

  // layer 3: Fin=2048, Fout=1024  (f32 path for error headroom)
  gemm256<false><<<dim3(1024 / 256, mb), gblk, 131072, stream>>>(hbf, (const ushort*)Wt3, bufA, N, 2048, 1024);
  compute_al<false><<<N, blk, 0, stream>>>(bufA, a3s, a3d, als, ald, 1024);
  float* hf32 = (float*)xwb;  // reuse as f32 out (L3 GEMM reads hbf only)
  aggregate<4, false, false><<<N, blk, 0, stream>>>(bufA, als, ald, rowptr, eidx, b3, hf32, 1024);

  normalize_kernel<<<N, blk, 0, stream>>>(hf32, (float*)d_out, 1024);
}

// Round 7
// 465.312 us; speedup vs baseline: 6.9112x; 1.0200x over previous
//
#include <hip/hip_runtime.h>
#include <hip/hip_bf16.h>
#include <math.h>

// ---------------------------------------------------------------------------
// 3-layer GAT forward. Round 7: GEMM -> 256x128 tile, BK=64, 8 waves,
// TRIPLE-buffered LDS, 2 phases/K-tile, counted vmcnt(6) (stage at t lands
// for t+2), st_16x32 swizzle (pre-swizzled global src + swizzled ds_read),
// setprio around MFMA clusters, bijective XCD-chunked block swizzle.
// Aggregation / softmax unchanged (validated R5/R6).
// ---------------------------------------------------------------------------

typedef __attribute__((ext_vector_type(8))) short short8;
typedef __attribute__((ext_vector_type(4))) float f32x4;

#define GLOAD_LDS16(g, l)                                            \
  __builtin_amdgcn_global_load_lds(                                  \
      (const __attribute__((address_space(1))) void*)(g),            \
      (__attribute__((address_space(3))) void*)(l), 16, 0, 0)

__device__ __forceinline__ float bf16_to_f32(ushort u) {
  return __uint_as_float(((unsigned int)u) << 16);
}

__device__ __forceinline__ float block_reduce_sum_bcast(float v) {
#pragma unroll
  for (int off = 32; off > 0; off >>= 1) v += __shfl_down(v, off, 64);
  __shared__ float tmp[4];
  __shared__ float res;
  int lane = threadIdx.x & 63, w = threadIdx.x >> 6;
  if (lane == 0) tmp[w] = v;
  __syncthreads();
  if (threadIdx.x == 0) res = tmp[0] + tmp[1] + tmp[2] + tmp[3];
  __syncthreads();
  float out = res;
  __syncthreads();
  return out;
}

__device__ __forceinline__ float block_reduce_max_bcast(float v) {
#pragma unroll
  for (int off = 32; off > 0; off >>= 1) v = fmaxf(v, __shfl_down(v, off, 64));
  __shared__ float tmpm[4];
  __shared__ float resm;
  int lane = threadIdx.x & 63, w = threadIdx.x >> 6;
  if (lane == 0) tmpm[w] = v;
  __syncthreads();
  if (threadIdx.x == 0) resm = fmaxf(fmaxf(tmpm[0], tmpm[1]), fmaxf(tmpm[2], tmpm[3]));
  __syncthreads();
  float out = resm;
  __syncthreads();
  return out;
}

// ---------------------------------------------------------------------------
// edge_index dtype detection (int64 vs int32), kept for robustness.
// ---------------------------------------------------------------------------
__global__ void detect_kernel(const int* __restrict__ ei32, int* __restrict__ flag) {
  __shared__ int cnt;
  if (threadIdx.x == 0) cnt = 0;
  __syncthreads();
  int zeros = 0;
  for (int i = threadIdx.x; i < 1024; i += 256) {
    if (ei32[2 * i + 1] == 0) zeros++;
  }
  atomicAdd(&cnt, zeros);
  __syncthreads();
  if (threadIdx.x == 0) *flag = (cnt > 900) ? 1 : 0;
}

__global__ void convert_kernel(const void* __restrict__ ei, const int* __restrict__ flag,
                               int E, int* __restrict__ src, int* __restrict__ dst) {
  int i = blockIdx.x * blockDim.x + threadIdx.x;
  if (i >= E) return;
  if (*flag) {
    const long long* p = (const long long*)ei;
    src[i] = (int)p[i];
    dst[i] = (int)p[E + i];
  } else {
    const int* p = (const int*)ei;
    src[i] = p[i];
    dst[i] = p[E + i];
  }
}

// ---------------------------------------------------------------------------
__global__ __launch_bounds__(256) void convert_f32_bf16(const float* __restrict__ in,
                                                        __hip_bfloat16* __restrict__ out,
                                                        int n) {
  int i = blockIdx.x * blockDim.x + threadIdx.x;
  if (i < n) out[i] = __float2bfloat16(in[i]);
}

// ---------------------------------------------------------------------------
// Transpose W [K][N] f32 -> Wt [N][K] bf16.  32x32 tiles, 256 threads.
// ---------------------------------------------------------------------------
__global__ __launch_bounds__(256) void transpose_w(const float* __restrict__ W,
                                                   __hip_bfloat16* __restrict__ Wt,
                                                   int K, int Nout) {
  __shared__ float t[32][33];
  int tx = threadIdx.x & 31, ty = threadIdx.x >> 5;  // 32 x 8
  int n0 = blockIdx.x * 32, k0 = blockIdx.y * 32;
#pragma unroll
  for (int i = 0; i < 4; ++i) {
    int k = k0 + ty + i * 8;
    t[ty + i * 8][tx] = W[(size_t)k * Nout + n0 + tx];
  }
  __syncthreads();
#pragma unroll
  for (int i = 0; i < 4; ++i) {
    int n = n0 + ty + i * 8;
    Wt[(size_t)n * K + k0 + tx] = __float2bfloat16(t[tx][ty + i * 8]);
  }
}

// ---------------------------------------------------------------------------
// C[M][Nout] = A[M][K](bf16) @ Bt[Nout][K](bf16)^T.
// BM=256, BN=128, BK=64, 512 threads (8 waves, 2M x 4N), TRIPLE-buffered LDS.
// Per K-tile: 2 phases (kk=0,1). Per phase each thread issues 3
// global_load_lds (A:2, B:1) for tile t+2, then vmcnt(6) (= the 6 loads of
// the two most recent phases stay in flight; everything older retired —
// stage(t,ph) is read at (t+2,ph), guaranteed by the wait at (t+1,ph)).
// Subtile = 16 rows x 32 cols (1 KiB): A subtile (sr,sc) at (sr*2+sc)*512,
// B subtile (sn,sc) at 16384+(sn*2+sc)*512 (ushort units) within a buffer.
// Write-side swizzle on the GLOBAL source chunk, read-side on ds_read chunk
// (both-sides st_16x32; LDS dest stays linear for global_load_lds).
// ---------------------------------------------------------------------------
template <bool BF16OUT>
__global__ __launch_bounds__(512, 2) void gemm_bn128(const ushort* __restrict__ A,
                                                     const ushort* __restrict__ Bt,
                                                     void* __restrict__ C,
                                                     int M, int K, int Nout) {
  constexpr int BUF = 16384 + 8192;  // ushorts per buffer (A 256x64 + B 128x64)
  extern __shared__ ushort lds[];
  const int tid = threadIdx.x;
  const int l = tid & 63, w = tid >> 6;
  const int wm = w >> 2, wn = w & 3;
  const int l15 = l & 15, lhi = l >> 4;

  // bijective XCD-chunked block swizzle (nwg % 8 == 0 for all our grids)
  int nwg = gridDim.x * gridDim.y;
  int lin = blockIdx.y * gridDim.x + blockIdx.x;
  if ((nwg & 7) == 0) lin = (lin & 7) * (nwg >> 3) + (lin >> 3);
  const int bx = lin % gridDim.x, by = lin / gridDim.x;
  const int row0 = by * 256, col0 = bx * 128;

  // write-side swizzle: lane l fills subtile byte l*16 (linear LDS dest);
  // fetches global chunk c8sw = (l&3) ^ (((l>>5)&1)<<1) of row (l>>2).
  const int c8sw = (l & 3) ^ (((l >> 5) & 1) << 1);
  const int lrow = l >> 2;
  // read-side swizzle: logical (row=l15, chunk=lhi) lives at chunk
  // lhi ^ ((l15>>3)&1)<<1.
  const int chsw = lhi ^ (((l15 >> 3) & 1) << 1);
  const int rd_off = l15 * 32 + chsw * 8;  // ushort units within subtile

  // staging assignment: A — wave stages subtile-rows sA0,sA0+1 (2 loads/phase);
  // B — wave stages subtile-row w (1 load/phase).
  const int sA0 = wm * 8 + wn * 2;
  const int sB0 = w;
  const ushort* ga[2][2];
  const ushort* gb[2];
#pragma unroll
  for (int sc = 0; sc < 2; ++sc) {
#pragma unroll
    for (int j = 0; j < 2; ++j) {
      int ar = min(row0 + (sA0 + j) * 16 + lrow, M - 1);  // clamp; masked at C-write
      ga[sc][j] = A + (size_t)ar * K + sc * 32 + c8sw * 8;
    }
    gb[sc] = Bt + (size_t)(col0 + sB0 * 16 + lrow) * K + sc * 32 + c8sw * 8;
  }

#define STAGE_PH(nb, kn, sc)                                                         \
  do {                                                                               \
    GLOAD_LDS16(ga[sc][0] + (kn), &lds[(nb)*BUF + ((sA0 + 0) * 2 + (sc)) * 512]);    \
    GLOAD_LDS16(ga[sc][1] + (kn), &lds[(nb)*BUF + ((sA0 + 1) * 2 + (sc)) * 512]);    \
    GLOAD_LDS16(gb[sc] + (kn), &lds[(nb)*BUF + 16384 + (sB0 * 2 + (sc)) * 512]);     \
  } while (0)

  f32x4 acc[8][2] = {};

#define PHASE(cbase, kk, STAGE_STMT)                                                 \
  do {                                                                               \
    short8 af[8], bf[2];                                                             \
    _Pragma("unroll") for (int m = 0; m < 8; ++m)                                    \
        af[m] = *(const short8*)(cbase + ((wm * 8 + m) * 2 + (kk)) * 512 + rd_off);  \
    _Pragma("unroll") for (int n = 0; n < 2; ++n)                                    \
        bf[n] = *(const short8*)(cbase + 16384 + ((wn * 2 + n) * 2 + (kk)) * 512 + rd_off); \
    STAGE_STMT;                                                                      \
    asm volatile("s_waitcnt vmcnt(6)" ::: "memory");                                 \
    __builtin_amdgcn_s_barrier();                                                    \
    __builtin_amdgcn_s_setprio(1);                                                   \
    _Pragma("unroll") for (int m = 0; m < 8; ++m)                                    \
        _Pragma("unroll") for (int n = 0; n < 2; ++n)                                \
            acc[m][n] = __builtin_amdgcn_mfma_f32_16x16x32_bf16(                     \
                af[m], bf[n], acc[m][n], 0, 0, 0);                                   \
    __builtin_amdgcn_s_setprio(0);                                                   \
    __builtin_amdgcn_s_barrier();                                                    \
  } while (0)

  const int nt = K >> 6;  // nt >= 4 for all layers here
  // prologue: stage tiles 0 and 1; wait for tile 0 (6 newest = tile 1 stay in flight)
  STAGE_PH(0, 0, 0);
  STAGE_PH(0, 0, 1);
  STAGE_PH(1, 64, 0);
  STAGE_PH(1, 64, 1);
  asm volatile("s_waitcnt vmcnt(6)" ::: "memory");
  __builtin_amdgcn_s_barrier();

  int cur = 0;
  for (int t = 0; t < nt; ++t) {
    const ushort* cb = &lds[cur * BUF];
    int nb = cur + 2; if (nb >= 3) nb -= 3;
    const bool pf = (t + 2) < nt;
    const int kn = (t + 2) << 6;
    PHASE(cb, 0, if (pf) STAGE_PH(nb, kn, 0));
    PHASE(cb, 1, if (pf) STAGE_PH(nb, kn, 1));
    cur = cur + 1; if (cur == 3) cur = 0;
  }

  // epilogue: D mapping col=lane&15, row=(lane>>4)*4+reg
#pragma unroll
  for (int mi = 0; mi < 8; ++mi) {
#pragma unroll
    for (int v = 0; v < 4; ++v) {
      int r = row0 + wm * 128 + mi * 16 + lhi * 4 + v;
      if (r < M) {
#pragma unroll
        for (int n = 0; n < 2; ++n) {
          size_t idx = (size_t)r * Nout + col0 + wn * 32 + n * 16 + l15;
          if (BF16OUT)
            ((__hip_bfloat16*)C)[idx] = __float2bfloat16(acc[mi][n][v]);
          else
            ((float*)C)[idx] = acc[mi][n][v];
        }
      }
    }
  }
#undef PHASE
#undef STAGE_PH
}

// ---------------------------------------------------------------------------
// al_src[n] = dot(xw[n,:], a_s); al_dst[n] = dot(xw[n,:], a_d)
// ---------------------------------------------------------------------------
template <bool BF16IN>
__global__ __launch_bounds__(256) void compute_al(const void* __restrict__ xw,
                                                  const float* __restrict__ a_s,
                                                  const float* __restrict__ a_d,
                                                  float* __restrict__ als,
                                                  float* __restrict__ ald, int F) {
  int n = blockIdx.x;
  float s1 = 0.f, s2 = 0.f;
  if (BF16IN) {
    const ushort* row = (const ushort*)xw + (size_t)n * F;
    int base = threadIdx.x * 8;  // 256*8 == 2048
    short8 v = *(const short8*)(row + base);
#pragma unroll
    for (int j = 0; j < 8; ++j) {
      float f = bf16_to_f32((ushort)v[j]);
      s1 += f * a_s[base + j];
      s2 += f * a_d[base + j];
    }
  } else {
    const float* row = (const float*)xw + (size_t)n * F;
    for (int f = threadIdx.x; f < F; f += 256) {
      float v = row[f];
      s1 += v * a_s[f];
      s2 += v * a_d[f];
    }
  }
  float r1 = block_reduce_sum_bcast(s1);
  float r2 = block_reduce_sum_bcast(s2);
  if (threadIdx.x == 0) {
    als[n] = r1;
    ald[n] = r2;
  }
}

// ---------------------------------------------------------------------------
// CSR build
// ---------------------------------------------------------------------------
__global__ void count_kernel(const int* __restrict__ dst, int* __restrict__ counts, int E) {
  int i = blockIdx.x * blockDim.x + threadIdx.x;
  if (i < E) atomicAdd(&counts[dst[i]], 1);
}

__global__ __launch_bounds__(1024) void scan_kernel(const int* __restrict__ counts,
                                                    int* __restrict__ rowptr,
                                                    int* __restrict__ cursor, int Nn) {
  __shared__ int part[1024];
  int tid = threadIdx.x;
  int chunk = (Nn + 1023) / 1024;
  int base = tid * chunk;
  int s = 0;
  for (int i = 0; i < chunk; ++i) {
    int idx = base + i;
    if (idx < Nn) s += counts[idx];
  }
  part[tid] = s;
  __syncthreads();
  for (int off = 1; off < 1024; off <<= 1) {
    int v = 0;
    if (tid >= off) v = part[tid - off];
    __syncthreads();
    if (tid >= off) part[tid] += v;
    __syncthreads();
  }
  int run = (tid == 0) ? 0 : part[tid - 1];
  for (int i = 0; i < chunk; ++i) {
    int idx = base + i;
    if (idx < Nn) {
      rowptr[idx] = run;
      cursor[idx] = run;
      run += counts[idx];
    }
  }
  if (tid == 1023) rowptr[Nn] = part[1023];
}

__global__ void fill_kernel(const int* __restrict__ src, const int* __restrict__ dst,
                            int* __restrict__ cursor, int* __restrict__ eidx, int E) {
  int i = blockIdx.x * blockDim.x + threadIdx.x;
  if (i < E) {
    int pos = atomicAdd(&cursor[dst[i]], 1);
    eidx[pos] = src[i];
  }
}

// ---------------------------------------------------------------------------
// Per-dst-node softmax attention + weighted gather + bias + ReLU.
// ---------------------------------------------------------------------------
template <int FPT, bool BF16IN, bool BF16OUT>
__global__ __launch_bounds__(256) void aggregate(const void* __restrict__ xw,
                                                 const float* __restrict__ als,
                                                 const float* __restrict__ ald,
                                                 const int* __restrict__ rowptr,
                                                 const int* __restrict__ eidx,
                                                 const float* __restrict__ bias,
                                                 void* __restrict__ out, int F) {
  int n = blockIdx.x;
  int tid = threadIdx.x;
  int beg = rowptr[n], end = rowptr[n + 1];
  int deg = end - beg;
  float aldn = ald[n];

  float lm = -INFINITY;
  for (int j = tid; j < deg; j += 256) {
    int s = eidx[beg + j];
    float e = als[s] + aldn;
    e = (e > 0.f) ? e : 0.2f * e;
    lm = fmaxf(lm, e);
  }
  if (tid == 0) {
    float e = als[n] + aldn;
    e = (e > 0.f) ? e : 0.2f * e;
    lm = fmaxf(lm, e);
  }
  float m = block_reduce_max_bcast(lm);

  float ls = 0.f;
  for (int j = tid; j < deg; j += 256) {
    int s = eidx[beg + j];
    float e = als[s] + aldn;
    e = (e > 0.f) ? e : 0.2f * e;
    ls += expf(e - m);
  }
  if (tid == 0) {
    float e = als[n] + aldn;
    e = (e > 0.f) ? e : 0.2f * e;
    ls += expf(e - m);
  }
  float denom = block_reduce_sum_bcast(ls) + 1e-16f;
  float inv_denom = 1.f / denom;

  float acc[FPT];
#pragma unroll
  for (int i = 0; i < FPT; ++i) acc[i] = 0.f;

  __shared__ float alpha_sh[256];
  __shared__ int src_sh[256];
  int total = deg + 1;
  for (int c0 = 0; c0 < total; c0 += 256) {
    int j = c0 + tid;
    if (j < total) {
      int s = (j < deg) ? eidx[beg + j] : n;
      float e = als[s] + aldn;
      e = (e > 0.f) ? e : 0.2f * e;
      alpha_sh[tid] = expf(e - m) * inv_denom;
      src_sh[tid] = s;
    }
    __syncthreads();
    int cn = min(256, total - c0);
    for (int jj = 0; jj < cn; ++jj) {
      float al = alpha_sh[jj];
      if (BF16IN) {
        const ushort* row = (const ushort*)xw + (size_t)src_sh[jj] * F;
#pragma unroll
        for (int i = 0; i < FPT / 2; ++i) {
          unsigned int u = *(const unsigned int*)(row + tid * 2 + i * 512);
          acc[2 * i]     += al * __uint_as_float((u & 0xffffu) << 16);
          acc[2 * i + 1] += al * __uint_as_float(u & 0xffff0000u);
        }
      } else {
        const float* row = (const float*)xw + (size_t)src_sh[jj] * F;
#pragma unroll
        for (int i = 0; i < FPT; ++i) acc[i] += al * row[tid + i * 256];
      }
    }
    __syncthreads();
  }

#pragma unroll
  for (int i = 0; i < FPT; ++i) {
    int col = BF16IN ? (tid * 2 + (i >> 1) * 512 + (i & 1)) : (tid + i * 256);
    float v = fmaxf(acc[i] + bias[col], 0.f);
    size_t idx = (size_t)n * F + col;
    if (BF16OUT)
      ((__hip_bfloat16*)out)[idx] = __float2bfloat16(v);
    else
      ((float*)out)[idx] = v;
  }
}

// ---------------------------------------------------------------------------
// Row L2 normalize (eps 1e-12), write f32.
// ---------------------------------------------------------------------------
__global__ __launch_bounds__(256) void normalize_kernel(const float* __restrict__ h,
                                                        float* __restrict__ out,
                                                        int F) {
  int n = blockIdx.x;
  const float* row = h + (size_t)n * F;
  float ss = 0.f;
  for (int f = threadIdx.x; f < F; f += 256) {
    float v = row[f];
    ss += v * v;
  }
  float tot = block_reduce_sum_bcast(ss);
  float inv = 1.f / fmaxf(sqrtf(tot), 1e-12f);
  for (int f = threadIdx.x; f < F; f += 256) {
    out[(size_t)n * F + f] = row[f] * inv;
  }
}

// ---------------------------------------------------------------------------
extern "C" void kernel_launch(void* const* d_in, const int* in_sizes, int n_in,
                              void* d_out, int out_size, void* d_ws, size_t ws_size,
                              hipStream_t stream) {
  const float* x   = (const float*)d_in[0];
  const void*  ei  = d_in[1];
  const float* W1  = (const float*)d_in[2];
  const float* W2  = (const float*)d_in[3];
  const float* W3  = (const float*)d_in[4];
  const float* a1s = (const float*)d_in[5];
  const float* a1d = (const float*)d_in[6];
  const float* a2s = (const float*)d_in[7];
  const float* a2d = (const float*)d_in[8];
  const float* a3s = (const float*)d_in[9];
  const float* a3d = (const float*)d_in[10];
  const float* b1  = (const float*)d_in[11];
  const float* b2  = (const float*)d_in[12];
  const float* b3  = (const float*)d_in[13];

  const int N = in_sizes[0] / 256;  // 10000
  const int E = in_sizes[1] / 2;    // 80000

  char* ws = (char*)d_ws;
  size_t off = 0;
  auto alloc = [&](size_t bytes) -> void* {
    void* p = ws + off;
    off += (bytes + 255) & ~(size_t)255;
    return p;
  };
  ushort* xwb = (ushort*)alloc((size_t)N * 2048 * 2);   // GEMM out bf16 (L1,L2); f32 agg out (L3)
  ushort* hbf = (ushort*)alloc((size_t)N * 2048 * 2);   // aggregated activations bf16
  float* bufA = (float*)alloc((size_t)N * 1024 * 4);    // L3 GEMM out f32
  __hip_bfloat16* xb  = (__hip_bfloat16*)alloc((size_t)N * 256 * 2);
  __hip_bfloat16* Wt1 = (__hip_bfloat16*)alloc((size_t)2048 * 256 * 2);
  __hip_bfloat16* Wt2 = (__hip_bfloat16*)alloc((size_t)2048 * 2048 * 2);
  __hip_bfloat16* Wt3 = (__hip_bfloat16*)alloc((size_t)1024 * 2048 * 2);
  float* als   = (float*)alloc((size_t)N * 4);
  float* ald   = (float*)alloc((size_t)N * 4);
  int* counts  = (int*)alloc((size_t)N * 4);
  int* rowptr  = (int*)alloc((size_t)(N + 1) * 4);
  int* cursor  = (int*)alloc((size_t)N * 4);
  int* eidx    = (int*)alloc((size_t)E * 4);
  int* src32   = (int*)alloc((size_t)E * 4);
  int* dst32   = (int*)alloc((size_t)E * 4);
  int* flag    = (int*)alloc(256);

  // allow 144 KiB dynamic LDS for the GEMM kernels (3 x 48 KiB buffers)
  static bool attr_done = false;
  if (!attr_done) {
    hipFuncSetAttribute((const void*)gemm_bn128<true>,
                        hipFuncAttributeMaxDynamicSharedMemorySize, 147456);
    hipFuncSetAttribute((const void*)gemm_bn128<false>,
                        hipFuncAttributeMaxDynamicSharedMemorySize, 147456);
    attr_done = true;
  }

  // edge_index dtype detect + convert; CSR build (by dst)
  detect_kernel<<<1, 256, 0, stream>>>((const int*)ei, flag);
  convert_kernel<<<(E + 255) / 256, 256, 0, stream>>>(ei, flag, E, src32, dst32);
  hipMemsetAsync(counts, 0, (size_t)N * 4, stream);
  count_kernel<<<(E + 255) / 256, 256, 0, stream>>>(dst32, counts, E);
  scan_kernel<<<1, 1024, 0, stream>>>(counts, rowptr, cursor, N);
  fill_kernel<<<(E + 255) / 256, 256, 0, stream>>>(src32, dst32, cursor, eidx, E);

  // bf16 prep
  convert_f32_bf16<<<(N * 256 + 255) / 256, 256, 0, stream>>>(x, xb, N * 256);
  transpose_w<<<dim3(2048 / 32, 256 / 32), 256, 0, stream>>>(W1, Wt1, 256, 2048);
  transpose_w<<<dim3(2048 / 32, 2048 / 32), 256, 0, stream>>>(W2, Wt2, 2048, 2048);
  transpose_w<<<dim3(1024 / 32, 2048 / 32), 256, 0, stream>>>(W3, Wt3, 2048, 1024);

  dim3 blk(256);
  dim3 gblk(512);
  int mb = (N + 255) / 256;  // 40

  // layer 1: Fin=256, Fout=2048   (bf16 xw path)   grid 16x40 = 640
  gemm_bn128<true><<<dim3(2048 / 128, mb), gblk, 147456, stream>>>((const ushort*)xb, (const ushort*)Wt1, xwb, N, 256, 2048);
  compute_al<true><<<N, blk, 0, stream>>>(xwb, a1s, a1d, als, ald, 2048);
  aggregate<8, true, true><<<N, blk, 0, stream>>>(xwb, als, ald, rowptr, eidx, b1, hbf, 2048);

  // layer 2: Fin=2048, Fout=2048  (bf16 xw path)   grid 16x40 = 640
  gemm_bn128<true><<<dim3(2048 / 128, mb), gblk, 147456, stream>>>(hbf, (const ushort*)Wt2, xwb, N, 2048, 2048);
  compute_al<true><<<N, blk, 0, stream>>>(xwb, a2s, a2d, als, ald, 2048);
  aggregate<8, true, true><<<N, blk, 0, stream>>>(xwb, als, ald, rowptr, eidx, b2, hbf, 2048);

  // layer 3: Fin=2048, Fout=1024  (f32 path)       grid 8x40 = 320
  gemm_bn128<false><<<dim3(1024 / 128, mb), gblk, 147456, stream>>>(hbf, (const ushort*)Wt3, bufA, N, 2048, 1024);
  compute_al<false><<<N, blk, 0, stream>>>(bufA, a3s, a3d, als, ald, 1024);
  float* hf32 = (float*)xwb;  // reuse as f32 out (L3 GEMM reads hbf only)
  aggregate<4, false, false><<<N, blk, 0, stream>>>(bufA, als, ald, rowptr, eidx, b3, hf32, 1024);

  normalize_kernel<<<N, blk, 0, stream>>>(hf32, (float*)d_out, 1024);
}